// Round 7
// baseline (395.301 us; speedup 1.0000x reference)
//
#include <hip/hip_runtime.h>
#include <math.h>

// ---------------------------------------------------------------------------
// GCN 3x GraphConv (DGL norm='both'), N=50000, E=800000, 256->128->128->64.
// R7: bucket fill via atomicExch instead of plain store. R5/R6 counters
// showed build_csr is bound by scattered partial-line PLAIN stores (800k x
// ~92B line writebacks = 74MB @ ~1TB/s = its whole 76us), while atomics are
// absorbed in L2 (zero write amplification). atomicExch puts the bucket
// write on the L2-atomic path -> lazy per-line writeback (~15MB).
// Replication (R6) reverted: proved neutral. No compact pass.
//   L1: M1 = f16(X*ns)@W1 ; H1s = relu(sum M1[src] *nd + b1)*ns
//   L2: agg2 = sum H1s[src] ; H2s = relu((agg2@W2)*nd + b2)*ns
//   L3: M3 = H2s@W3 ; out = sum M3[src]*nd + b3
// CAP=64: in-deg ~ Poisson(16), P(>64) ~ 1e-19; guarded anyway.
// ---------------------------------------------------------------------------

typedef _Float16 half8 __attribute__((ext_vector_type(8)));
typedef _Float16 half4v __attribute__((ext_vector_type(4)));
typedef float floatx4 __attribute__((ext_vector_type(4)));

#define CAP 64

// One pass: out-deg count + in-deg count + bucket fill (all on atomic path).
__global__ __launch_bounds__(256) void build_csr(
    const int* __restrict__ src, const int* __restrict__ dst,
    int* __restrict__ cntO, int* __restrict__ cntI,
    int* __restrict__ bucket, int E)
{
    int e = blockIdx.x * 256 + threadIdx.x;
    if (e < E) {
        int s = src[e];
        int d = dst[e];
        atomicAdd(&cntO[s], 1);
        int p = atomicAdd(&cntI[d], 1);
        if (p < CAP)
            atomicExch(&bucket[(size_t)d * CAP + p], s);  // L2-absorbed write
    }
}

// Fused f16 transpose of W1,W2,W3: WT[n*K+k] = (f16) W[k*NC+n]
__global__ __launch_bounds__(256) void wprep(
    const float* __restrict__ W1, const float* __restrict__ W2,
    const float* __restrict__ W3, _Float16* __restrict__ WT1,
    _Float16* __restrict__ WT2, _Float16* __restrict__ WT3)
{
    int i = blockIdx.x * 256 + threadIdx.x;
    if (i < 256 * 128) {
        int k = i / 128, n = i - k * 128;
        WT1[(size_t)n * 256 + k] = (_Float16)W1[i];
    } else if (i < 256 * 128 + 128 * 128) {
        int r = i - 256 * 128;
        int k = r / 128, n = r - k * 128;
        WT2[(size_t)n * 128 + k] = (_Float16)W2[r];
    } else if (i < 256 * 128 + 128 * 128 + 128 * 64) {
        int r = i - 256 * 128 - 128 * 128;
        int k = r / 64, n = r - k * 64;
        WT3[(size_t)n * 128 + k] = (_Float16)W3[r];
    }
}

// ---------------------------------------------------------------------------
// MFMA GEMM: C[M,NC] f16 = A[M,K] @ W, W as WT[NC,K] f16. (verified R4-R6)
// A_FP32: fp32 A scaled by rsqrt(cnt_rs[row]) on the fly.
// Epilogue: *rsqrt(cnt_nd)? + bias?, relu?, *rsqrt(cnt_ns)?
// ---------------------------------------------------------------------------
template<int K, int NC, bool A_FP32>
__global__ __launch_bounds__(256) void gemm_mfma(
    const void* __restrict__ A_, const _Float16* __restrict__ WT,
    const int* __restrict__ cnt_rs,
    const int* __restrict__ cnt_nd, const float* __restrict__ bias,
    int do_relu, const int* __restrict__ cnt_ns,
    _Float16* __restrict__ C, int M)
{
    constexpr int NT = NC / 16;
    const int tid  = threadIdx.x;
    const int wave = tid >> 6;
    const int lane = tid & 63;
    const int quad = lane >> 4;
    const int l16  = lane & 15;

    const int row_base = blockIdx.x * 64 + wave * 16;
    int arow = row_base + l16;
    if (arow > M - 1) arow = M - 1;   // clamp; stores guarded below

    floatx4 acc[NT];
#pragma unroll
    for (int t = 0; t < NT; t++) acc[t] = (floatx4){0.f, 0.f, 0.f, 0.f};

    float rs = 1.0f;
    if (A_FP32 && cnt_rs) rs = rsqrtf(fmaxf((float)cnt_rs[arow], 1.0f));

    const float*    Af = (const float*)A_;
    const _Float16* Ah = (const _Float16*)A_;

    for (int k0 = 0; k0 < K; k0 += 32) {
        half8 a;
        if (A_FP32) {
            const float* p = &Af[(size_t)arow * K + k0 + quad * 8];
            float4 f0 = *(const float4*)p;
            float4 f1 = *(const float4*)(p + 4);
            a[0] = (_Float16)(f0.x * rs); a[1] = (_Float16)(f0.y * rs);
            a[2] = (_Float16)(f0.z * rs); a[3] = (_Float16)(f0.w * rs);
            a[4] = (_Float16)(f1.x * rs); a[5] = (_Float16)(f1.y * rs);
            a[6] = (_Float16)(f1.z * rs); a[7] = (_Float16)(f1.w * rs);
        } else {
            a = *(const half8*)&Ah[(size_t)arow * K + k0 + quad * 8];
        }
#pragma unroll
        for (int t = 0; t < NT; t++) {
            half8 b = *(const half8*)&WT[(size_t)(t * 16 + l16) * K + k0 + quad * 8];
            acc[t] = __builtin_amdgcn_mfma_f32_16x16x32_f16(a, b, acc[t], 0, 0, 0);
        }
    }

#pragma unroll
    for (int t = 0; t < NT; t++) {
        int col = t * 16 + l16;
        float bv = bias ? bias[col] : 0.f;
#pragma unroll
        for (int r = 0; r < 4; r++) {
            int row_o = row_base + quad * 4 + r;
            if (row_o < M) {
                float v = acc[t][r];
                if (cnt_nd) v *= rsqrtf(fmaxf((float)cnt_nd[row_o], 1.0f));
                v += bv;
                if (do_relu) v = fmaxf(v, 0.f);
                if (cnt_ns) v *= rsqrtf(fmaxf((float)cnt_ns[row_o], 1.0f));
                C[(size_t)row_o * NC + col] = (_Float16)v;
            }
        }
    }
}

// ---------------------------------------------------------------------------
// F=128 gather: one wave/node, 2 groups x 32 lanes, half4 slices,
// 8 row-loads in flight per group (16/wave).
// ---------------------------------------------------------------------------
__global__ __launch_bounds__(256) void gather128(
    const _Float16* __restrict__ msg, const int* __restrict__ cntI,
    const int* __restrict__ cntO, const int* __restrict__ bucket,
    const float* __restrict__ bias, int do_relu, int use_nd, int use_ns,
    _Float16* __restrict__ out, int N)
{
    int node = (blockIdx.x * 256 + threadIdx.x) >> 6;
    if (node >= N) return;
    int lane = threadIdx.x & 63;
    int grp = lane >> 5, l32 = lane & 31;

    int len = min(cntI[node], CAP);
    const int* bl = bucket + (size_t)node * CAP;
    const half4v* mp = (const half4v*)msg;   // 32 half4 per 128-f16 row

    float a0 = 0.f, a1 = 0.f, a2 = 0.f, a3 = 0.f;
    int j = grp;
    for (; j + 14 < len; j += 16) {
        int s0 = bl[j],      s1 = bl[j + 2],  s2 = bl[j + 4],  s3 = bl[j + 6];
        int s4 = bl[j + 8],  s5 = bl[j + 10], s6 = bl[j + 12], s7 = bl[j + 14];
        half4v v0 = mp[(size_t)s0 * 32 + l32];
        half4v v1 = mp[(size_t)s1 * 32 + l32];
        half4v v2 = mp[(size_t)s2 * 32 + l32];
        half4v v3 = mp[(size_t)s3 * 32 + l32];
        half4v v4 = mp[(size_t)s4 * 32 + l32];
        half4v v5 = mp[(size_t)s5 * 32 + l32];
        half4v v6 = mp[(size_t)s6 * 32 + l32];
        half4v v7 = mp[(size_t)s7 * 32 + l32];
        a0 += ((float)v0[0] + (float)v1[0]) + ((float)v2[0] + (float)v3[0])
            + ((float)v4[0] + (float)v5[0]) + ((float)v6[0] + (float)v7[0]);
        a1 += ((float)v0[1] + (float)v1[1]) + ((float)v2[1] + (float)v3[1])
            + ((float)v4[1] + (float)v5[1]) + ((float)v6[1] + (float)v7[1]);
        a2 += ((float)v0[2] + (float)v1[2]) + ((float)v2[2] + (float)v3[2])
            + ((float)v4[2] + (float)v5[2]) + ((float)v6[2] + (float)v7[2]);
        a3 += ((float)v0[3] + (float)v1[3]) + ((float)v2[3] + (float)v3[3])
            + ((float)v4[3] + (float)v5[3]) + ((float)v6[3] + (float)v7[3]);
    }
    for (; j < len; j += 2) {
        half4v v = mp[(size_t)bl[j] * 32 + l32];
        a0 += (float)v[0]; a1 += (float)v[1];
        a2 += (float)v[2]; a3 += (float)v[3];
    }
    a0 += __shfl_xor(a0, 32);
    a1 += __shfl_xor(a1, 32);
    a2 += __shfl_xor(a2, 32);
    a3 += __shfl_xor(a3, 32);

    if (grp == 0) {
        float sc = use_nd ? rsqrtf(fmaxf((float)len, 1.0f)) : 1.0f;
        float pp = use_ns ? rsqrtf(fmaxf((float)cntO[node], 1.0f)) : 1.0f;
        float b0 = bias ? bias[l32 * 4 + 0] : 0.f;
        float b1 = bias ? bias[l32 * 4 + 1] : 0.f;
        float b2 = bias ? bias[l32 * 4 + 2] : 0.f;
        float b3 = bias ? bias[l32 * 4 + 3] : 0.f;
        float r0 = a0 * sc + b0, r1 = a1 * sc + b1;
        float r2 = a2 * sc + b2, r3 = a3 * sc + b3;
        if (do_relu) {
            r0 = fmaxf(r0, 0.f); r1 = fmaxf(r1, 0.f);
            r2 = fmaxf(r2, 0.f); r3 = fmaxf(r3, 0.f);
        }
        half4v rv;
        rv[0] = (_Float16)(r0 * pp); rv[1] = (_Float16)(r1 * pp);
        rv[2] = (_Float16)(r2 * pp); rv[3] = (_Float16)(r3 * pp);
        ((half4v*)out)[(size_t)node * 32 + l32] = rv;
    }
}

// F=64 gather: 4 groups x 16 lanes, 4 row-loads in flight per group, fp32 out.
__global__ __launch_bounds__(256) void gather64(
    const _Float16* __restrict__ msg, const int* __restrict__ cntI,
    const int* __restrict__ bucket, const float* __restrict__ bias,
    float* __restrict__ out, int N)
{
    int node = (blockIdx.x * 256 + threadIdx.x) >> 6;
    if (node >= N) return;
    int lane = threadIdx.x & 63;
    int grp = lane >> 4, l16 = lane & 15;

    int len = min(cntI[node], CAP);
    const int* bl = bucket + (size_t)node * CAP;
    const half4v* mp = (const half4v*)msg;   // 16 half4 per 64-f16 row

    float a0 = 0.f, a1 = 0.f, a2 = 0.f, a3 = 0.f;
    int j = grp;
    for (; j + 12 < len; j += 16) {
        int s0 = bl[j], s1 = bl[j + 4], s2 = bl[j + 8], s3 = bl[j + 12];
        half4v v0 = mp[(size_t)s0 * 16 + l16];
        half4v v1 = mp[(size_t)s1 * 16 + l16];
        half4v v2 = mp[(size_t)s2 * 16 + l16];
        half4v v3 = mp[(size_t)s3 * 16 + l16];
        a0 += ((float)v0[0] + (float)v1[0]) + ((float)v2[0] + (float)v3[0]);
        a1 += ((float)v0[1] + (float)v1[1]) + ((float)v2[1] + (float)v3[1]);
        a2 += ((float)v0[2] + (float)v1[2]) + ((float)v2[2] + (float)v3[2]);
        a3 += ((float)v0[3] + (float)v1[3]) + ((float)v2[3] + (float)v3[3]);
    }
    for (; j < len; j += 4) {
        half4v v = mp[(size_t)bl[j] * 16 + l16];
        a0 += (float)v[0]; a1 += (float)v[1];
        a2 += (float)v[2]; a3 += (float)v[3];
    }
    a0 += __shfl_xor(a0, 16); a0 += __shfl_xor(a0, 32);
    a1 += __shfl_xor(a1, 16); a1 += __shfl_xor(a1, 32);
    a2 += __shfl_xor(a2, 16); a2 += __shfl_xor(a2, 32);
    a3 += __shfl_xor(a3, 16); a3 += __shfl_xor(a3, 32);

    if (grp == 0) {
        float sc = rsqrtf(fmaxf((float)len, 1.0f));
        float4 r;
        r.x = a0 * sc + bias[l16 * 4 + 0];
        r.y = a1 * sc + bias[l16 * 4 + 1];
        r.z = a2 * sc + bias[l16 * 4 + 2];
        r.w = a3 * sc + bias[l16 * 4 + 3];
        ((float4*)out)[(size_t)node * 16 + l16] = r;
    }
}

extern "C" void kernel_launch(void* const* d_in, const int* in_sizes, int n_in,
                              void* d_out, int out_size, void* d_ws, size_t ws_size,
                              hipStream_t stream)
{
    const float* X  = (const float*)d_in[0];
    const float* W1 = (const float*)d_in[1];
    const float* b1 = (const float*)d_in[2];
    const float* W2 = (const float*)d_in[3];
    const float* b2 = (const float*)d_in[4];
    const float* W3 = (const float*)d_in[5];
    const float* b3 = (const float*)d_in[6];
    const int*   src = (const int*)d_in[7];
    const int*   dst = (const int*)d_in[8];

    const int N = in_sizes[0] / 256;   // 50000
    const int E = in_sizes[7];         // 800000

    char* base = (char*)d_ws;
    size_t cur = 0;
    auto alloc = [&](size_t bytes) -> void* {
        void* p = base + cur;
        cur += (bytes + 255) & ~(size_t)255;
        return p;
    };
    int* cnt2   = (int*)alloc((size_t)2 * N * 4);   // cntO|cntI contiguous
    int* cntO   = cnt2;
    int* cntI   = cnt2 + N;
    int* bucket = (int*)alloc((size_t)N * CAP * 4); // 12.8 MB
    _Float16* Bh0 = (_Float16*)alloc((size_t)N * 128 * 2);
    _Float16* Bh1 = (_Float16*)alloc((size_t)N * 128 * 2);
    _Float16* WT1 = (_Float16*)alloc((size_t)256 * 128 * 2);
    _Float16* WT2 = (_Float16*)alloc((size_t)128 * 128 * 2);
    _Float16* WT3 = (_Float16*)alloc((size_t)128 * 64 * 2);

    const int eblk = (E + 255) / 256;
    const int gblk = (N + 63) / 64;
    const int wblk = (N + 3) / 4;

    hipMemsetAsync(cnt2, 0, 2 * (size_t)N * sizeof(int), stream);
    wprep<<<(256*128 + 128*128 + 128*64 + 255) / 256, 256, 0, stream>>>(
        W1, W2, W3, WT1, WT2, WT3);
    build_csr<<<eblk, 256, 0, stream>>>(src, dst, cntO, cntI, bucket, E);

    // ---- Layer 1 ----
    gemm_mfma<256, 128, true><<<gblk, 256, 0, stream>>>(
        X, WT1, cntO, nullptr, nullptr, 0, nullptr, Bh0, N);
    gather128<<<wblk, 256, 0, stream>>>(
        Bh0, cntI, cntO, bucket, b1, 1, 1, 1, Bh1, N);      // H1s

    // ---- Layer 2 ----
    gather128<<<wblk, 256, 0, stream>>>(
        Bh1, cntI, cntO, bucket, nullptr, 0, 0, 0, Bh0, N); // agg2
    gemm_mfma<128, 128, false><<<gblk, 256, 0, stream>>>(
        Bh0, WT2, nullptr, cntI, b2, 1, cntO, Bh1, N);      // H2s

    // ---- Layer 3 ----
    gemm_mfma<128, 64, false><<<gblk, 256, 0, stream>>>(
        Bh1, WT3, nullptr, nullptr, nullptr, 0, nullptr, Bh0, N);  // M3
    gather64<<<wblk, 256, 0, stream>>>(
        Bh0, cntI, bucket, b3, (float*)d_out, N);
}

// Round 8
// 362.064 us; speedup vs baseline: 1.0918x; 1.0918x over previous
//
#include <hip/hip_runtime.h>
#include <math.h>

// ---------------------------------------------------------------------------
// GCN 3x GraphConv (DGL norm='both'), N=50000, E=800000, 256->128->128->64.
// R8: two-pass LDS-binned CSR build. R5-R7 proved scattered partial-line
// writes (plain OR atomic) each write ~32B through to HBM (WRITE_SIZE
// invariant 74MB, ~1TB/s floor). Binning makes every global write a
// coalesced full-line burst:
//   bin_dst:     tile->LDS count/scan/stage by dst>>8 -> linear runs out
//   build_lists: block per coarse bucket, LDS per-node bin -> full-line rows
//   bin_src/count_src: same two-pass for out-degrees
// Layers (f16 intermediates, MFMA, scale folding; verified R4/R5):
//   L1: M1 = f16(X*ns)@W1 ; H1s = relu(sum M1[src] *nd + b1)*ns
//   L2: agg2 = sum H1s[src] ; H2s = relu((agg2@W2)*nd + b2)*ns
//   L3: M3 = H2s@W3 ; out = sum M3[src]*nd + b3
// ---------------------------------------------------------------------------

typedef _Float16 half8 __attribute__((ext_vector_type(8)));
typedef _Float16 half4v __attribute__((ext_vector_type(4)));
typedef float floatx4 __attribute__((ext_vector_type(4)));

#define TILE 4096   // edges per bin tile
#define BCAP 8192   // per-coarse-bucket capacity (avg 4096, sigma 64)
#define PKW  64     // packed list width per node = 128B = one L2 line
#define EPT  16     // edges per thread in bin pass (TILE/256)

// ---- pass 1a: bin (src,dst) pairs by dst>>8, coalesced run write-out ----
__global__ __launch_bounds__(256) void bin_dst(
    const int* __restrict__ src, const int* __restrict__ dst, int E, int NB,
    int* __restrict__ gcur, ushort2* __restrict__ binned)
{
    __shared__ int lcnt[256];
    __shared__ int loff[256];
    __shared__ int cur[256];
    __shared__ int lbase[256];
    __shared__ int wtot[4];
    __shared__ ushort2 stage[TILE];

    const int tid = threadIdx.x, lane = tid & 63, wave = tid >> 6;
    const int tile0 = blockIdx.x * TILE;
    const int tn = min(TILE, E - tile0);

    lcnt[tid] = 0;
    __syncthreads();

    unsigned short es[EPT], ed[EPT];
    unsigned char  eb[EPT];
    int nl = 0;
    for (int i = tid; i < tn; i += 256) {
        int s = src[tile0 + i], d = dst[tile0 + i];
        int b = d >> 8;
        es[nl] = (unsigned short)s; ed[nl] = (unsigned short)d;
        eb[nl] = (unsigned char)b; nl++;
        atomicAdd(&lcnt[b], 1);
    }
    __syncthreads();

    // block exclusive scan of lcnt[0..255]
    int v = lcnt[tid], x = v;
#pragma unroll
    for (int o = 1; o < 64; o <<= 1) {
        int t = __shfl_up(x, o, 64);
        if (lane >= o) x += t;
    }
    if (lane == 63) wtot[wave] = x;
    __syncthreads();
    if (tid == 0) {
        int a = 0;
#pragma unroll
        for (int w = 0; w < 4; w++) { int t = wtot[w]; wtot[w] = a; a += t; }
    }
    __syncthreads();
    int excl = x - v + wtot[wave];
    loff[tid] = excl;
    cur[tid]  = excl;
    __syncthreads();

    // place into stage grouped by bucket
    for (int j = 0; j < nl; j++) {
        int p = atomicAdd(&cur[eb[j]], 1);
        ushort2 u; u.x = es[j]; u.y = ed[j];
        stage[p] = u;
    }
    // reserve global space per bucket
    if (tid < NB && lcnt[tid] > 0)
        lbase[tid] = atomicAdd(&gcur[tid], lcnt[tid]);
    __syncthreads();

    // linear coalesced write-out; bucket of i via binary search on loff
    for (int i = tid; i < tn; i += 256) {
        int lo = 0, hi = NB - 1;
        while (lo < hi) {
            int mid = (lo + hi + 1) >> 1;
            if (loff[mid] <= i) lo = mid; else hi = mid - 1;
        }
        int b = lo;
        int gi = lbase[b] + (i - loff[b]);
        if (gi < BCAP)
            binned[(size_t)b * BCAP + gi] = stage[i];
    }
}

// ---- pass 2a: per coarse bucket, bin by exact dst -> packed rows + cntI ----
__global__ __launch_bounds__(256) void build_lists(
    const ushort2* __restrict__ binned, const int* __restrict__ gcur,
    unsigned short* __restrict__ packed, int* __restrict__ cntI, int N)
{
    __shared__ unsigned short stage[256 * PKW];   // 32 KB
    __shared__ int lcnt[256];
    const int tid = threadIdx.x;
    const int b = blockIdx.x;
    const int node0 = b << 8;

    lcnt[tid] = 0;
    __syncthreads();

    const int n = min(gcur[b], BCAP);
    const ushort2* eb = binned + (size_t)b * BCAP;
    for (int i = tid; i < n; i += 256) {
        ushort2 e = eb[i];
        int ld = (int)e.y - node0;            // 0..255 by construction
        int p = atomicAdd(&lcnt[ld], 1);
        if (p < PKW) stage[ld * PKW + p] = e.x;
    }
    __syncthreads();

    int node = node0 + tid;
    if (node < N) cntI[node] = min(lcnt[tid], PKW);

    // full-line row copies: wave w handles rows w, w+4, ...
    const int wave = tid >> 6, lane = tid & 63;
    for (int ld = wave; ld < 256; ld += 4) {
        int nd = node0 + ld;
        if (nd < N)
            packed[(size_t)nd * PKW + lane] = stage[ld * PKW + lane];
    }
}

// ---- pass 1b: bin src values by src>>8 ----
__global__ __launch_bounds__(256) void bin_src(
    const int* __restrict__ src, int E, int NB,
    int* __restrict__ gcur, unsigned short* __restrict__ binned)
{
    __shared__ int lcnt[256];
    __shared__ int loff[256];
    __shared__ int cur[256];
    __shared__ int lbase[256];
    __shared__ int wtot[4];
    __shared__ unsigned short stage[TILE];

    const int tid = threadIdx.x, lane = tid & 63, wave = tid >> 6;
    const int tile0 = blockIdx.x * TILE;
    const int tn = min(TILE, E - tile0);

    lcnt[tid] = 0;
    __syncthreads();

    unsigned short es[EPT];
    unsigned char  eb[EPT];
    int nl = 0;
    for (int i = tid; i < tn; i += 256) {
        int s = src[tile0 + i];
        es[nl] = (unsigned short)s;
        eb[nl] = (unsigned char)(s >> 8); nl++;
        atomicAdd(&lcnt[s >> 8], 1);
    }
    __syncthreads();

    int v = lcnt[tid], x = v;
#pragma unroll
    for (int o = 1; o < 64; o <<= 1) {
        int t = __shfl_up(x, o, 64);
        if (lane >= o) x += t;
    }
    if (lane == 63) wtot[wave] = x;
    __syncthreads();
    if (tid == 0) {
        int a = 0;
#pragma unroll
        for (int w = 0; w < 4; w++) { int t = wtot[w]; wtot[w] = a; a += t; }
    }
    __syncthreads();
    int excl = x - v + wtot[wave];
    loff[tid] = excl;
    cur[tid]  = excl;
    __syncthreads();

    for (int j = 0; j < nl; j++) {
        int p = atomicAdd(&cur[eb[j]], 1);
        stage[p] = es[j];
    }
    if (tid < NB && lcnt[tid] > 0)
        lbase[tid] = atomicAdd(&gcur[tid], lcnt[tid]);
    __syncthreads();

    for (int i = tid; i < tn; i += 256) {
        int lo = 0, hi = NB - 1;
        while (lo < hi) {
            int mid = (lo + hi + 1) >> 1;
            if (loff[mid] <= i) lo = mid; else hi = mid - 1;
        }
        int b = lo;
        int gi = lbase[b] + (i - loff[b]);
        if (gi < BCAP)
            binned[(size_t)b * BCAP + gi] = stage[i];
    }
}

// ---- pass 2b: per coarse bucket, histogram -> cntO ----
__global__ __launch_bounds__(256) void count_src(
    const unsigned short* __restrict__ binned, const int* __restrict__ gcur,
    int* __restrict__ cntO, int N)
{
    __shared__ int h[256];
    const int tid = threadIdx.x;
    const int b = blockIdx.x;
    const int node0 = b << 8;
    h[tid] = 0;
    __syncthreads();
    const int n = min(gcur[b], BCAP);
    const unsigned short* eb = binned + (size_t)b * BCAP;
    for (int i = tid; i < n; i += 256)
        atomicAdd(&h[(int)eb[i] - node0], 1);
    __syncthreads();
    int node = node0 + tid;
    if (node < N) cntO[node] = h[tid];
}

// Fused f16 transpose of W1,W2,W3: WT[n*K+k] = (f16) W[k*NC+n]
__global__ __launch_bounds__(256) void wprep(
    const float* __restrict__ W1, const float* __restrict__ W2,
    const float* __restrict__ W3, _Float16* __restrict__ WT1,
    _Float16* __restrict__ WT2, _Float16* __restrict__ WT3)
{
    int i = blockIdx.x * 256 + threadIdx.x;
    if (i < 256 * 128) {
        int k = i / 128, n = i - k * 128;
        WT1[(size_t)n * 256 + k] = (_Float16)W1[i];
    } else if (i < 256 * 128 + 128 * 128) {
        int r = i - 256 * 128;
        int k = r / 128, n = r - k * 128;
        WT2[(size_t)n * 128 + k] = (_Float16)W2[r];
    } else if (i < 256 * 128 + 128 * 128 + 128 * 64) {
        int r = i - 256 * 128 - 128 * 128;
        int k = r / 64, n = r - k * 64;
        WT3[(size_t)n * 128 + k] = (_Float16)W3[r];
    }
}

// ---------------------------------------------------------------------------
// MFMA GEMM: C[M,NC] f16 = A[M,K] @ W, W as WT[NC,K] f16. (verified R4-R7)
// ---------------------------------------------------------------------------
template<int K, int NC, bool A_FP32>
__global__ __launch_bounds__(256) void gemm_mfma(
    const void* __restrict__ A_, const _Float16* __restrict__ WT,
    const int* __restrict__ cnt_rs,
    const int* __restrict__ cnt_nd, const float* __restrict__ bias,
    int do_relu, const int* __restrict__ cnt_ns,
    _Float16* __restrict__ C, int M)
{
    constexpr int NT = NC / 16;
    const int tid  = threadIdx.x;
    const int wave = tid >> 6;
    const int lane = tid & 63;
    const int quad = lane >> 4;
    const int l16  = lane & 15;

    const int row_base = blockIdx.x * 64 + wave * 16;
    int arow = row_base + l16;
    if (arow > M - 1) arow = M - 1;

    floatx4 acc[NT];
#pragma unroll
    for (int t = 0; t < NT; t++) acc[t] = (floatx4){0.f, 0.f, 0.f, 0.f};

    float rs = 1.0f;
    if (A_FP32 && cnt_rs) rs = rsqrtf(fmaxf((float)cnt_rs[arow], 1.0f));

    const float*    Af = (const float*)A_;
    const _Float16* Ah = (const _Float16*)A_;

    for (int k0 = 0; k0 < K; k0 += 32) {
        half8 a;
        if (A_FP32) {
            const float* p = &Af[(size_t)arow * K + k0 + quad * 8];
            float4 f0 = *(const float4*)p;
            float4 f1 = *(const float4*)(p + 4);
            a[0] = (_Float16)(f0.x * rs); a[1] = (_Float16)(f0.y * rs);
            a[2] = (_Float16)(f0.z * rs); a[3] = (_Float16)(f0.w * rs);
            a[4] = (_Float16)(f1.x * rs); a[5] = (_Float16)(f1.y * rs);
            a[6] = (_Float16)(f1.z * rs); a[7] = (_Float16)(f1.w * rs);
        } else {
            a = *(const half8*)&Ah[(size_t)arow * K + k0 + quad * 8];
        }
#pragma unroll
        for (int t = 0; t < NT; t++) {
            half8 b = *(const half8*)&WT[(size_t)(t * 16 + l16) * K + k0 + quad * 8];
            acc[t] = __builtin_amdgcn_mfma_f32_16x16x32_f16(a, b, acc[t], 0, 0, 0);
        }
    }

#pragma unroll
    for (int t = 0; t < NT; t++) {
        int col = t * 16 + l16;
        float bv = bias ? bias[col] : 0.f;
#pragma unroll
        for (int r = 0; r < 4; r++) {
            int row_o = row_base + quad * 4 + r;
            if (row_o < M) {
                float v = acc[t][r];
                if (cnt_nd) v *= rsqrtf(fmaxf((float)cnt_nd[row_o], 1.0f));
                v += bv;
                if (do_relu) v = fmaxf(v, 0.f);
                if (cnt_ns) v *= rsqrtf(fmaxf((float)cnt_ns[row_o], 1.0f));
                C[(size_t)row_o * NC + col] = (_Float16)v;
            }
        }
    }
}

// ---------------------------------------------------------------------------
// F=128 gather: one wave/node, 2 groups x 32 lanes, half4 slices,
// 8 row-loads in flight per group. packed ushort list (stride PKW).
// ---------------------------------------------------------------------------
__global__ __launch_bounds__(256) void gather128(
    const _Float16* __restrict__ msg, const int* __restrict__ cntI,
    const int* __restrict__ cntO, const unsigned short* __restrict__ packed,
    const float* __restrict__ bias, int do_relu, int use_nd, int use_ns,
    _Float16* __restrict__ out, int N)
{
    int node = (blockIdx.x * 256 + threadIdx.x) >> 6;
    if (node >= N) return;
    int lane = threadIdx.x & 63;
    int grp = lane >> 5, l32 = lane & 31;

    int len = cntI[node];
    const unsigned short* bl = packed + (size_t)node * PKW;
    const half4v* mp = (const half4v*)msg;

    float a0 = 0.f, a1 = 0.f, a2 = 0.f, a3 = 0.f;
    int j = grp;
    for (; j + 14 < len; j += 16) {
        int s0 = bl[j],      s1 = bl[j + 2],  s2 = bl[j + 4],  s3 = bl[j + 6];
        int s4 = bl[j + 8],  s5 = bl[j + 10], s6 = bl[j + 12], s7 = bl[j + 14];
        half4v v0 = mp[(size_t)s0 * 32 + l32];
        half4v v1 = mp[(size_t)s1 * 32 + l32];
        half4v v2 = mp[(size_t)s2 * 32 + l32];
        half4v v3 = mp[(size_t)s3 * 32 + l32];
        half4v v4 = mp[(size_t)s4 * 32 + l32];
        half4v v5 = mp[(size_t)s5 * 32 + l32];
        half4v v6 = mp[(size_t)s6 * 32 + l32];
        half4v v7 = mp[(size_t)s7 * 32 + l32];
        a0 += ((float)v0[0] + (float)v1[0]) + ((float)v2[0] + (float)v3[0])
            + ((float)v4[0] + (float)v5[0]) + ((float)v6[0] + (float)v7[0]);
        a1 += ((float)v0[1] + (float)v1[1]) + ((float)v2[1] + (float)v3[1])
            + ((float)v4[1] + (float)v5[1]) + ((float)v6[1] + (float)v7[1]);
        a2 += ((float)v0[2] + (float)v1[2]) + ((float)v2[2] + (float)v3[2])
            + ((float)v4[2] + (float)v5[2]) + ((float)v6[2] + (float)v7[2]);
        a3 += ((float)v0[3] + (float)v1[3]) + ((float)v2[3] + (float)v3[3])
            + ((float)v4[3] + (float)v5[3]) + ((float)v6[3] + (float)v7[3]);
    }
    for (; j < len; j += 2) {
        half4v v = mp[(size_t)bl[j] * 32 + l32];
        a0 += (float)v[0]; a1 += (float)v[1];
        a2 += (float)v[2]; a3 += (float)v[3];
    }
    a0 += __shfl_xor(a0, 32);
    a1 += __shfl_xor(a1, 32);
    a2 += __shfl_xor(a2, 32);
    a3 += __shfl_xor(a3, 32);

    if (grp == 0) {
        float sc = use_nd ? rsqrtf(fmaxf((float)len, 1.0f)) : 1.0f;
        float pp = use_ns ? rsqrtf(fmaxf((float)cntO[node], 1.0f)) : 1.0f;
        float b0 = bias ? bias[l32 * 4 + 0] : 0.f;
        float b1 = bias ? bias[l32 * 4 + 1] : 0.f;
        float b2 = bias ? bias[l32 * 4 + 2] : 0.f;
        float b3 = bias ? bias[l32 * 4 + 3] : 0.f;
        float r0 = a0 * sc + b0, r1 = a1 * sc + b1;
        float r2 = a2 * sc + b2, r3 = a3 * sc + b3;
        if (do_relu) {
            r0 = fmaxf(r0, 0.f); r1 = fmaxf(r1, 0.f);
            r2 = fmaxf(r2, 0.f); r3 = fmaxf(r3, 0.f);
        }
        half4v rv;
        rv[0] = (_Float16)(r0 * pp); rv[1] = (_Float16)(r1 * pp);
        rv[2] = (_Float16)(r2 * pp); rv[3] = (_Float16)(r3 * pp);
        ((half4v*)out)[(size_t)node * 32 + l32] = rv;
    }
}

// F=64 gather: 4 groups x 16 lanes, fp32 float4 out.
__global__ __launch_bounds__(256) void gather64(
    const _Float16* __restrict__ msg, const int* __restrict__ cntI,
    const unsigned short* __restrict__ packed, const float* __restrict__ bias,
    float* __restrict__ out, int N)
{
    int node = (blockIdx.x * 256 + threadIdx.x) >> 6;
    if (node >= N) return;
    int lane = threadIdx.x & 63;
    int grp = lane >> 4, l16 = lane & 15;

    int len = cntI[node];
    const unsigned short* bl = packed + (size_t)node * PKW;
    const half4v* mp = (const half4v*)msg;

    float a0 = 0.f, a1 = 0.f, a2 = 0.f, a3 = 0.f;
    int j = grp;
    for (; j + 12 < len; j += 16) {
        int s0 = bl[j], s1 = bl[j + 4], s2 = bl[j + 8], s3 = bl[j + 12];
        half4v v0 = mp[(size_t)s0 * 16 + l16];
        half4v v1 = mp[(size_t)s1 * 16 + l16];
        half4v v2 = mp[(size_t)s2 * 16 + l16];
        half4v v3 = mp[(size_t)s3 * 16 + l16];
        a0 += ((float)v0[0] + (float)v1[0]) + ((float)v2[0] + (float)v3[0]);
        a1 += ((float)v0[1] + (float)v1[1]) + ((float)v2[1] + (float)v3[1]);
        a2 += ((float)v0[2] + (float)v1[2]) + ((float)v2[2] + (float)v3[2]);
        a3 += ((float)v0[3] + (float)v1[3]) + ((float)v2[3] + (float)v3[3]);
    }
    for (; j < len; j += 4) {
        half4v v = mp[(size_t)bl[j] * 16 + l16];
        a0 += (float)v[0]; a1 += (float)v[1];
        a2 += (float)v[2]; a3 += (float)v[3];
    }
    a0 += __shfl_xor(a0, 16); a0 += __shfl_xor(a0, 32);
    a1 += __shfl_xor(a1, 16); a1 += __shfl_xor(a1, 32);
    a2 += __shfl_xor(a2, 16); a2 += __shfl_xor(a2, 32);
    a3 += __shfl_xor(a3, 16); a3 += __shfl_xor(a3, 32);

    if (grp == 0) {
        float sc = rsqrtf(fmaxf((float)len, 1.0f));
        float4 r;
        r.x = a0 * sc + bias[l16 * 4 + 0];
        r.y = a1 * sc + bias[l16 * 4 + 1];
        r.z = a2 * sc + bias[l16 * 4 + 2];
        r.w = a3 * sc + bias[l16 * 4 + 3];
        ((float4*)out)[(size_t)node * 16 + l16] = r;
    }
}

extern "C" void kernel_launch(void* const* d_in, const int* in_sizes, int n_in,
                              void* d_out, int out_size, void* d_ws, size_t ws_size,
                              hipStream_t stream)
{
    const float* X  = (const float*)d_in[0];
    const float* W1 = (const float*)d_in[1];
    const float* b1 = (const float*)d_in[2];
    const float* W2 = (const float*)d_in[3];
    const float* b2 = (const float*)d_in[4];
    const float* W3 = (const float*)d_in[5];
    const float* b3 = (const float*)d_in[6];
    const int*   src = (const int*)d_in[7];
    const int*   dst = (const int*)d_in[8];

    const int N = in_sizes[0] / 256;   // 50000
    const int E = in_sizes[7];         // 800000
    const int NB = (N + 255) >> 8;     // 196 coarse buckets

    char* base = (char*)d_ws;
    size_t cur = 0;
    auto alloc = [&](size_t bytes) -> void* {
        void* p = base + cur;
        cur += (bytes + 255) & ~(size_t)255;
        return p;
    };
    int* gcur2 = (int*)alloc((size_t)2 * 256 * 4);           // gcurD | gcurS
    int* gcurD = gcur2;
    int* gcurS = gcur2 + 256;
    ushort2*        binD   = (ushort2*)alloc((size_t)NB * BCAP * 4);
    unsigned short* binS   = (unsigned short*)alloc((size_t)NB * BCAP * 2);
    unsigned short* packed = (unsigned short*)alloc((size_t)N * PKW * 2);
    int* cntO = (int*)alloc((size_t)N * 4);
    int* cntI = (int*)alloc((size_t)N * 4);
    _Float16* Bh0 = (_Float16*)alloc((size_t)N * 128 * 2);
    _Float16* Bh1 = (_Float16*)alloc((size_t)N * 128 * 2);
    _Float16* WT1 = (_Float16*)alloc((size_t)256 * 128 * 2);
    _Float16* WT2 = (_Float16*)alloc((size_t)128 * 128 * 2);
    _Float16* WT3 = (_Float16*)alloc((size_t)128 * 64 * 2);

    const int tblk = (E + TILE - 1) / TILE;   // 196 tiles
    const int gblk = (N + 63) / 64;
    const int wblk = (N + 3) / 4;

    hipMemsetAsync(gcur2, 0, 2 * 256 * sizeof(int), stream);
    wprep<<<(256*128 + 128*128 + 128*64 + 255) / 256, 256, 0, stream>>>(
        W1, W2, W3, WT1, WT2, WT3);
    bin_dst<<<tblk, 256, 0, stream>>>(src, dst, E, NB, gcurD, binD);
    build_lists<<<NB, 256, 0, stream>>>(binD, gcurD, packed, cntI, N);
    bin_src<<<tblk, 256, 0, stream>>>(src, E, NB, gcurS, binS);
    count_src<<<NB, 256, 0, stream>>>(binS, gcurS, cntO, N);

    // ---- Layer 1 ----
    gemm_mfma<256, 128, true><<<gblk, 256, 0, stream>>>(
        X, WT1, cntO, nullptr, nullptr, 0, nullptr, Bh0, N);
    gather128<<<wblk, 256, 0, stream>>>(
        Bh0, cntI, cntO, packed, b1, 1, 1, 1, Bh1, N);      // H1s

    // ---- Layer 2 ----
    gather128<<<wblk, 256, 0, stream>>>(
        Bh1, cntI, cntO, packed, nullptr, 0, 0, 0, Bh0, N); // agg2
    gemm_mfma<128, 128, false><<<gblk, 256, 0, stream>>>(
        Bh0, WT2, nullptr, cntI, b2, 1, cntO, Bh1, N);      // H2s

    // ---- Layer 3 ----
    gemm_mfma<128, 64, false><<<gblk, 256, 0, stream>>>(
        Bh1, WT3, nullptr, nullptr, nullptr, 0, nullptr, Bh0, N);  // M3
    gather64<<<wblk, 256, 0, stream>>>(
        Bh0, cntI, packed, b3, (float*)d_out, N);
}

// Round 9
// 343.125 us; speedup vs baseline: 1.1521x; 1.0552x over previous
//
#include <hip/hip_runtime.h>
#include <math.h>

// ---------------------------------------------------------------------------
// GCN 3x GraphConv (DGL norm='both'), N=50000, E=800000, 256->128->128->64.
// R9: LDS-staged MFMA GEMM. R8 showed gemm1 latency-bound (MfmaUtil 2%,
// Occ 21%): each 16-row wave re-streamed 64KB WT from L2. Now: block =
// 128 rows, 4 waves x 2 m-tiles; WT chunk (NCx128, +8-half pad) staged in
// LDS once; B frags via ds_read_b128. Build/gathers = R8 (binned CSR).
//   L1: M1 = f16(X*ns)@W1 ; H1s = relu(sum M1[src] *nd + b1)*ns
//   L2: agg2 = sum H1s[src] ; H2s = relu((agg2@W2)*nd + b2)*ns
//   L3: M3 = H2s@W3 ; out = sum M3[src]*nd + b3
// ---------------------------------------------------------------------------

typedef _Float16 half8 __attribute__((ext_vector_type(8)));
typedef _Float16 half4v __attribute__((ext_vector_type(4)));
typedef float floatx4 __attribute__((ext_vector_type(4)));

#define TILE 4096   // edges per bin tile
#define BCAP 8192   // per-coarse-bucket capacity (avg 4096)
#define PKW  64     // packed list width per node = 128B line
#define EPT  16     // edges per thread in bin pass

// ---- pass 1a: bin (src,dst) by dst>>8, coalesced run write-out ----
__global__ __launch_bounds__(256) void bin_dst(
    const int* __restrict__ src, const int* __restrict__ dst, int E, int NB,
    int* __restrict__ gcur, ushort2* __restrict__ binned)
{
    __shared__ int lcnt[256];
    __shared__ int loff[256];
    __shared__ int cur[256];
    __shared__ int lbase[256];
    __shared__ int wtot[4];
    __shared__ ushort2 stage[TILE];

    const int tid = threadIdx.x, lane = tid & 63, wave = tid >> 6;
    const int tile0 = blockIdx.x * TILE;
    const int tn = min(TILE, E - tile0);

    lcnt[tid] = 0;
    __syncthreads();

    unsigned short es[EPT], ed[EPT];
    unsigned char  eb[EPT];
    int nl = 0;
    for (int i = tid; i < tn; i += 256) {
        int s = src[tile0 + i], d = dst[tile0 + i];
        int b = d >> 8;
        es[nl] = (unsigned short)s; ed[nl] = (unsigned short)d;
        eb[nl] = (unsigned char)b; nl++;
        atomicAdd(&lcnt[b], 1);
    }
    __syncthreads();

    int v = lcnt[tid], x = v;
#pragma unroll
    for (int o = 1; o < 64; o <<= 1) {
        int t = __shfl_up(x, o, 64);
        if (lane >= o) x += t;
    }
    if (lane == 63) wtot[wave] = x;
    __syncthreads();
    if (tid == 0) {
        int a = 0;
#pragma unroll
        for (int w = 0; w < 4; w++) { int t = wtot[w]; wtot[w] = a; a += t; }
    }
    __syncthreads();
    int excl = x - v + wtot[wave];
    loff[tid] = excl;
    cur[tid]  = excl;
    __syncthreads();

    for (int j = 0; j < nl; j++) {
        int p = atomicAdd(&cur[eb[j]], 1);
        ushort2 u; u.x = es[j]; u.y = ed[j];
        stage[p] = u;
    }
    if (tid < NB && lcnt[tid] > 0)
        lbase[tid] = atomicAdd(&gcur[tid], lcnt[tid]);
    __syncthreads();

    for (int i = tid; i < tn; i += 256) {
        int lo = 0, hi = NB - 1;
        while (lo < hi) {
            int mid = (lo + hi + 1) >> 1;
            if (loff[mid] <= i) lo = mid; else hi = mid - 1;
        }
        int b = lo;
        int gi = lbase[b] + (i - loff[b]);
        if (gi < BCAP)
            binned[(size_t)b * BCAP + gi] = stage[i];
    }
}

// ---- pass 2a: per coarse bucket, exact-dst bin -> packed rows + cntI ----
__global__ __launch_bounds__(256) void build_lists(
    const ushort2* __restrict__ binned, const int* __restrict__ gcur,
    unsigned short* __restrict__ packed, int* __restrict__ cntI, int N)
{
    __shared__ unsigned short stage[256 * PKW];
    __shared__ int lcnt[256];
    const int tid = threadIdx.x;
    const int b = blockIdx.x;
    const int node0 = b << 8;

    lcnt[tid] = 0;
    __syncthreads();

    const int n = min(gcur[b], BCAP);
    const ushort2* eb = binned + (size_t)b * BCAP;
    for (int i = tid; i < n; i += 256) {
        ushort2 e = eb[i];
        int ld = (int)e.y - node0;
        int p = atomicAdd(&lcnt[ld], 1);
        if (p < PKW) stage[ld * PKW + p] = e.x;
    }
    __syncthreads();

    int node = node0 + tid;
    if (node < N) cntI[node] = min(lcnt[tid], PKW);

    const int wave = tid >> 6, lane = tid & 63;
    for (int ld = wave; ld < 256; ld += 4) {
        int nd = node0 + ld;
        if (nd < N)
            packed[(size_t)nd * PKW + lane] = stage[ld * PKW + lane];
    }
}

// ---- pass 1b: bin src values by src>>8 ----
__global__ __launch_bounds__(256) void bin_src(
    const int* __restrict__ src, int E, int NB,
    int* __restrict__ gcur, unsigned short* __restrict__ binned)
{
    __shared__ int lcnt[256];
    __shared__ int loff[256];
    __shared__ int cur[256];
    __shared__ int lbase[256];
    __shared__ int wtot[4];
    __shared__ unsigned short stage[TILE];

    const int tid = threadIdx.x, lane = tid & 63, wave = tid >> 6;
    const int tile0 = blockIdx.x * TILE;
    const int tn = min(TILE, E - tile0);

    lcnt[tid] = 0;
    __syncthreads();

    unsigned short es[EPT];
    unsigned char  eb[EPT];
    int nl = 0;
    for (int i = tid; i < tn; i += 256) {
        int s = src[tile0 + i];
        es[nl] = (unsigned short)s;
        eb[nl] = (unsigned char)(s >> 8); nl++;
        atomicAdd(&lcnt[s >> 8], 1);
    }
    __syncthreads();

    int v = lcnt[tid], x = v;
#pragma unroll
    for (int o = 1; o < 64; o <<= 1) {
        int t = __shfl_up(x, o, 64);
        if (lane >= o) x += t;
    }
    if (lane == 63) wtot[wave] = x;
    __syncthreads();
    if (tid == 0) {
        int a = 0;
#pragma unroll
        for (int w = 0; w < 4; w++) { int t = wtot[w]; wtot[w] = a; a += t; }
    }
    __syncthreads();
    int excl = x - v + wtot[wave];
    loff[tid] = excl;
    cur[tid]  = excl;
    __syncthreads();

    for (int j = 0; j < nl; j++) {
        int p = atomicAdd(&cur[eb[j]], 1);
        stage[p] = es[j];
    }
    if (tid < NB && lcnt[tid] > 0)
        lbase[tid] = atomicAdd(&gcur[tid], lcnt[tid]);
    __syncthreads();

    for (int i = tid; i < tn; i += 256) {
        int lo = 0, hi = NB - 1;
        while (lo < hi) {
            int mid = (lo + hi + 1) >> 1;
            if (loff[mid] <= i) lo = mid; else hi = mid - 1;
        }
        int b = lo;
        int gi = lbase[b] + (i - loff[b]);
        if (gi < BCAP)
            binned[(size_t)b * BCAP + gi] = stage[i];
    }
}

// ---- pass 2b: per coarse bucket histogram -> cntO ----
__global__ __launch_bounds__(256) void count_src(
    const unsigned short* __restrict__ binned, const int* __restrict__ gcur,
    int* __restrict__ cntO, int N)
{
    __shared__ int h[256];
    const int tid = threadIdx.x;
    const int b = blockIdx.x;
    const int node0 = b << 8;
    h[tid] = 0;
    __syncthreads();
    const int n = min(gcur[b], BCAP);
    const unsigned short* eb = binned + (size_t)b * BCAP;
    for (int i = tid; i < n; i += 256)
        atomicAdd(&h[(int)eb[i] - node0], 1);
    __syncthreads();
    int node = node0 + tid;
    if (node < N) cntO[node] = h[tid];
}

// Fused f16 transpose of W1,W2,W3: WT[n*K+k] = (f16) W[k*NC+n]
__global__ __launch_bounds__(256) void wprep(
    const float* __restrict__ W1, const float* __restrict__ W2,
    const float* __restrict__ W3, _Float16* __restrict__ WT1,
    _Float16* __restrict__ WT2, _Float16* __restrict__ WT3)
{
    int i = blockIdx.x * 256 + threadIdx.x;
    if (i < 256 * 128) {
        int k = i / 128, n = i - k * 128;
        WT1[(size_t)n * 256 + k] = (_Float16)W1[i];
    } else if (i < 256 * 128 + 128 * 128) {
        int r = i - 256 * 128;
        int k = r / 128, n = r - k * 128;
        WT2[(size_t)n * 128 + k] = (_Float16)W2[r];
    } else if (i < 256 * 128 + 128 * 128 + 128 * 64) {
        int r = i - 256 * 128 - 128 * 128;
        int k = r / 64, n = r - k * 64;
        WT3[(size_t)n * 128 + k] = (_Float16)W3[r];
    }
}

// ---------------------------------------------------------------------------
// LDS-staged MFMA GEMM: C[M,NC] f16 = A[M,K] @ W (WT[NC,K] f16).
// Block = 256 thr (4 waves) x 128 rows; wave = 2 m-tiles of 16 rows.
// WT staged per 128-wide K-chunk into LDS (row stride KC+8 halfs: 16B
// aligned, 2-way bank pattern = free). B frags: ds_read_b128.
// Fragment layouts verified R4-R8 (16x16x32: A[m=l16][k=quad*8+j],
// B[k=quad*8+j][n=l16], D col=l16,row=quad*4+reg).
// ---------------------------------------------------------------------------
template<int K, int NC, bool A_FP32>
__global__ __launch_bounds__(256) void gemm_mfma(
    const void* __restrict__ A_, const _Float16* __restrict__ WT,
    const int* __restrict__ cnt_rs,
    const int* __restrict__ cnt_nd, const float* __restrict__ bias,
    int do_relu, const int* __restrict__ cnt_ns,
    _Float16* __restrict__ C, int M)
{
    constexpr int NT  = NC / 16;
    constexpr int KC  = 128;          // K-chunk width
    constexpr int LDW = KC + 8;       // LDS row stride (halfs)
    __shared__ _Float16 Bs[NC * LDW]; // NC=128: 34.8KB, NC=64: 17.4KB

    const int tid  = threadIdx.x;
    const int wave = tid >> 6;
    const int lane = tid & 63;
    const int quad = lane >> 4;
    const int l16  = lane & 15;

    const int row_base = blockIdx.x * 128 + wave * 32;
    const int ar0 = min(row_base + l16, M - 1);
    const int ar1 = min(row_base + 16 + l16, M - 1);

    floatx4 acc[2][NT];
#pragma unroll
    for (int m = 0; m < 2; m++)
#pragma unroll
        for (int t = 0; t < NT; t++)
            acc[m][t] = (floatx4){0.f, 0.f, 0.f, 0.f};

    float rs0 = 1.0f, rs1 = 1.0f;
    if (A_FP32 && cnt_rs) {
        rs0 = rsqrtf(fmaxf((float)cnt_rs[ar0], 1.0f));
        rs1 = rsqrtf(fmaxf((float)cnt_rs[ar1], 1.0f));
    }

    const float*    Af = (const float*)A_;
    const _Float16* Ah = (const _Float16*)A_;

    for (int kc = 0; kc < K; kc += KC) {
        // stage WT[:, kc..kc+KC) into LDS: NC rows x KC halfs, half8 chunks
#pragma unroll
        for (int s = tid; s < NC * (KC / 8); s += 256) {
            int row  = s >> 4;          // KC/8 = 16
            int col8 = s & 15;
            half8 v = *(const half8*)&WT[(size_t)row * K + kc + col8 * 8];
            *(half8*)&Bs[row * LDW + col8 * 8] = v;
        }
        __syncthreads();
#pragma unroll
        for (int k0 = 0; k0 < KC; k0 += 32) {
            half8 a0, a1;
            if (A_FP32) {
                const float* p0 = &Af[(size_t)ar0 * K + kc + k0 + quad * 8];
                const float* p1 = &Af[(size_t)ar1 * K + kc + k0 + quad * 8];
                float4 f0 = *(const float4*)p0;
                float4 f1 = *(const float4*)(p0 + 4);
                float4 g0 = *(const float4*)p1;
                float4 g1 = *(const float4*)(p1 + 4);
                a0[0] = (_Float16)(f0.x * rs0); a0[1] = (_Float16)(f0.y * rs0);
                a0[2] = (_Float16)(f0.z * rs0); a0[3] = (_Float16)(f0.w * rs0);
                a0[4] = (_Float16)(f1.x * rs0); a0[5] = (_Float16)(f1.y * rs0);
                a0[6] = (_Float16)(f1.z * rs0); a0[7] = (_Float16)(f1.w * rs0);
                a1[0] = (_Float16)(g0.x * rs1); a1[1] = (_Float16)(g0.y * rs1);
                a1[2] = (_Float16)(g0.z * rs1); a1[3] = (_Float16)(g0.w * rs1);
                a1[4] = (_Float16)(g1.x * rs1); a1[5] = (_Float16)(g1.y * rs1);
                a1[6] = (_Float16)(g1.z * rs1); a1[7] = (_Float16)(g1.w * rs1);
            } else {
                a0 = *(const half8*)&Ah[(size_t)ar0 * K + kc + k0 + quad * 8];
                a1 = *(const half8*)&Ah[(size_t)ar1 * K + kc + k0 + quad * 8];
            }
#pragma unroll
            for (int t = 0; t < NT; t++) {
                half8 b = *(const half8*)&Bs[(t * 16 + l16) * LDW + k0 + quad * 8];
                acc[0][t] = __builtin_amdgcn_mfma_f32_16x16x32_f16(a0, b, acc[0][t], 0, 0, 0);
                acc[1][t] = __builtin_amdgcn_mfma_f32_16x16x32_f16(a1, b, acc[1][t], 0, 0, 0);
            }
        }
        __syncthreads();
    }

#pragma unroll
    for (int m = 0; m < 2; m++) {
#pragma unroll
        for (int t = 0; t < NT; t++) {
            int col = t * 16 + l16;
            float bv = bias ? bias[col] : 0.f;
#pragma unroll
            for (int r = 0; r < 4; r++) {
                int row_o = row_base + m * 16 + quad * 4 + r;
                if (row_o < M) {
                    float v = acc[m][t][r];
                    if (cnt_nd) v *= rsqrtf(fmaxf((float)cnt_nd[row_o], 1.0f));
                    v += bv;
                    if (do_relu) v = fmaxf(v, 0.f);
                    if (cnt_ns) v *= rsqrtf(fmaxf((float)cnt_ns[row_o], 1.0f));
                    C[(size_t)row_o * NC + col] = (_Float16)v;
                }
            }
        }
    }
}

// ---------------------------------------------------------------------------
// F=128 gather: one wave/node, 2 groups x 32 lanes, half4 slices,
// 8 row-loads in flight per group. packed ushort list (stride PKW).
// ---------------------------------------------------------------------------
__global__ __launch_bounds__(256) void gather128(
    const _Float16* __restrict__ msg, const int* __restrict__ cntI,
    const int* __restrict__ cntO, const unsigned short* __restrict__ packed,
    const float* __restrict__ bias, int do_relu, int use_nd, int use_ns,
    _Float16* __restrict__ out, int N)
{
    int node = (blockIdx.x * 256 + threadIdx.x) >> 6;
    if (node >= N) return;
    int lane = threadIdx.x & 63;
    int grp = lane >> 5, l32 = lane & 31;

    int len = cntI[node];
    const unsigned short* bl = packed + (size_t)node * PKW;
    const half4v* mp = (const half4v*)msg;

    float a0 = 0.f, a1 = 0.f, a2 = 0.f, a3 = 0.f;
    int j = grp;
    for (; j + 14 < len; j += 16) {
        int s0 = bl[j],      s1 = bl[j + 2],  s2 = bl[j + 4],  s3 = bl[j + 6];
        int s4 = bl[j + 8],  s5 = bl[j + 10], s6 = bl[j + 12], s7 = bl[j + 14];
        half4v v0 = mp[(size_t)s0 * 32 + l32];
        half4v v1 = mp[(size_t)s1 * 32 + l32];
        half4v v2 = mp[(size_t)s2 * 32 + l32];
        half4v v3 = mp[(size_t)s3 * 32 + l32];
        half4v v4 = mp[(size_t)s4 * 32 + l32];
        half4v v5 = mp[(size_t)s5 * 32 + l32];
        half4v v6 = mp[(size_t)s6 * 32 + l32];
        half4v v7 = mp[(size_t)s7 * 32 + l32];
        a0 += ((float)v0[0] + (float)v1[0]) + ((float)v2[0] + (float)v3[0])
            + ((float)v4[0] + (float)v5[0]) + ((float)v6[0] + (float)v7[0]);
        a1 += ((float)v0[1] + (float)v1[1]) + ((float)v2[1] + (float)v3[1])
            + ((float)v4[1] + (float)v5[1]) + ((float)v6[1] + (float)v7[1]);
        a2 += ((float)v0[2] + (float)v1[2]) + ((float)v2[2] + (float)v3[2])
            + ((float)v4[2] + (float)v5[2]) + ((float)v6[2] + (float)v7[2]);
        a3 += ((float)v0[3] + (float)v1[3]) + ((float)v2[3] + (float)v3[3])
            + ((float)v4[3] + (float)v5[3]) + ((float)v6[3] + (float)v7[3]);
    }
    for (; j < len; j += 2) {
        half4v v = mp[(size_t)bl[j] * 32 + l32];
        a0 += (float)v[0]; a1 += (float)v[1];
        a2 += (float)v[2]; a3 += (float)v[3];
    }
    a0 += __shfl_xor(a0, 32);
    a1 += __shfl_xor(a1, 32);
    a2 += __shfl_xor(a2, 32);
    a3 += __shfl_xor(a3, 32);

    if (grp == 0) {
        float sc = use_nd ? rsqrtf(fmaxf((float)len, 1.0f)) : 1.0f;
        float pp = use_ns ? rsqrtf(fmaxf((float)cntO[node], 1.0f)) : 1.0f;
        float b0 = bias ? bias[l32 * 4 + 0] : 0.f;
        float b1 = bias ? bias[l32 * 4 + 1] : 0.f;
        float b2 = bias ? bias[l32 * 4 + 2] : 0.f;
        float b3 = bias ? bias[l32 * 4 + 3] : 0.f;
        float r0 = a0 * sc + b0, r1 = a1 * sc + b1;
        float r2 = a2 * sc + b2, r3 = a3 * sc + b3;
        if (do_relu) {
            r0 = fmaxf(r0, 0.f); r1 = fmaxf(r1, 0.f);
            r2 = fmaxf(r2, 0.f); r3 = fmaxf(r3, 0.f);
        }
        half4v rv;
        rv[0] = (_Float16)(r0 * pp); rv[1] = (_Float16)(r1 * pp);
        rv[2] = (_Float16)(r2 * pp); rv[3] = (_Float16)(r3 * pp);
        ((half4v*)out)[(size_t)node * 32 + l32] = rv;
    }
}

// F=64 gather: 4 groups x 16 lanes, fp32 float4 out.
__global__ __launch_bounds__(256) void gather64(
    const _Float16* __restrict__ msg, const int* __restrict__ cntI,
    const unsigned short* __restrict__ packed, const float* __restrict__ bias,
    float* __restrict__ out, int N)
{
    int node = (blockIdx.x * 256 + threadIdx.x) >> 6;
    if (node >= N) return;
    int lane = threadIdx.x & 63;
    int grp = lane >> 4, l16 = lane & 15;

    int len = cntI[node];
    const unsigned short* bl = packed + (size_t)node * PKW;
    const half4v* mp = (const half4v*)msg;

    float a0 = 0.f, a1 = 0.f, a2 = 0.f, a3 = 0.f;
    int j = grp;
    for (; j + 12 < len; j += 16) {
        int s0 = bl[j], s1 = bl[j + 4], s2 = bl[j + 8], s3 = bl[j + 12];
        half4v v0 = mp[(size_t)s0 * 16 + l16];
        half4v v1 = mp[(size_t)s1 * 16 + l16];
        half4v v2 = mp[(size_t)s2 * 16 + l16];
        half4v v3 = mp[(size_t)s3 * 16 + l16];
        a0 += ((float)v0[0] + (float)v1[0]) + ((float)v2[0] + (float)v3[0]);
        a1 += ((float)v0[1] + (float)v1[1]) + ((float)v2[1] + (float)v3[1]);
        a2 += ((float)v0[2] + (float)v1[2]) + ((float)v2[2] + (float)v3[2]);
        a3 += ((float)v0[3] + (float)v1[3]) + ((float)v2[3] + (float)v3[3]);
    }
    for (; j < len; j += 4) {
        half4v v = mp[(size_t)bl[j] * 16 + l16];
        a0 += (float)v[0]; a1 += (float)v[1];
        a2 += (float)v[2]; a3 += (float)v[3];
    }
    a0 += __shfl_xor(a0, 16); a0 += __shfl_xor(a0, 32);
    a1 += __shfl_xor(a1, 16); a1 += __shfl_xor(a1, 32);
    a2 += __shfl_xor(a2, 16); a2 += __shfl_xor(a2, 32);
    a3 += __shfl_xor(a3, 16); a3 += __shfl_xor(a3, 32);

    if (grp == 0) {
        float sc = rsqrtf(fmaxf((float)len, 1.0f));
        float4 r;
        r.x = a0 * sc + bias[l16 * 4 + 0];
        r.y = a1 * sc + bias[l16 * 4 + 1];
        r.z = a2 * sc + bias[l16 * 4 + 2];
        r.w = a3 * sc + bias[l16 * 4 + 3];
        ((float4*)out)[(size_t)node * 16 + l16] = r;
    }
}

extern "C" void kernel_launch(void* const* d_in, const int* in_sizes, int n_in,
                              void* d_out, int out_size, void* d_ws, size_t ws_size,
                              hipStream_t stream)
{
    const float* X  = (const float*)d_in[0];
    const float* W1 = (const float*)d_in[1];
    const float* b1 = (const float*)d_in[2];
    const float* W2 = (const float*)d_in[3];
    const float* b2 = (const float*)d_in[4];
    const float* W3 = (const float*)d_in[5];
    const float* b3 = (const float*)d_in[6];
    const int*   src = (const int*)d_in[7];
    const int*   dst = (const int*)d_in[8];

    const int N = in_sizes[0] / 256;   // 50000
    const int E = in_sizes[7];         // 800000
    const int NB = (N + 255) >> 8;     // 196 coarse buckets

    char* base = (char*)d_ws;
    size_t cur = 0;
    auto alloc = [&](size_t bytes) -> void* {
        void* p = base + cur;
        cur += (bytes + 255) & ~(size_t)255;
        return p;
    };
    int* gcur2 = (int*)alloc((size_t)2 * 256 * 4);
    int* gcurD = gcur2;
    int* gcurS = gcur2 + 256;
    ushort2*        binD   = (ushort2*)alloc((size_t)NB * BCAP * 4);
    unsigned short* binS   = (unsigned short*)alloc((size_t)NB * BCAP * 2);
    unsigned short* packed = (unsigned short*)alloc((size_t)N * PKW * 2);
    int* cntO = (int*)alloc((size_t)N * 4);
    int* cntI = (int*)alloc((size_t)N * 4);
    _Float16* Bh0 = (_Float16*)alloc((size_t)N * 128 * 2);
    _Float16* Bh1 = (_Float16*)alloc((size_t)N * 128 * 2);
    _Float16* WT1 = (_Float16*)alloc((size_t)256 * 128 * 2);
    _Float16* WT2 = (_Float16*)alloc((size_t)128 * 128 * 2);
    _Float16* WT3 = (_Float16*)alloc((size_t)128 * 64 * 2);

    const int tblk = (E + TILE - 1) / TILE;
    const int gblk = (N + 127) / 128;
    const int wblk = (N + 3) / 4;

    hipMemsetAsync(gcur2, 0, 2 * 256 * sizeof(int), stream);
    wprep<<<(256*128 + 128*128 + 128*64 + 255) / 256, 256, 0, stream>>>(
        W1, W2, W3, WT1, WT2, WT3);
    bin_dst<<<tblk, 256, 0, stream>>>(src, dst, E, NB, gcurD, binD);
    build_lists<<<NB, 256, 0, stream>>>(binD, gcurD, packed, cntI, N);
    bin_src<<<tblk, 256, 0, stream>>>(src, E, NB, gcurS, binS);
    count_src<<<NB, 256, 0, stream>>>(binS, gcurS, cntO, N);

    // ---- Layer 1 ----
    gemm_mfma<256, 128, true><<<gblk, 256, 0, stream>>>(
        X, WT1, cntO, nullptr, nullptr, 0, nullptr, Bh0, N);
    gather128<<<wblk, 256, 0, stream>>>(
        Bh0, cntI, cntO, packed, b1, 1, 1, 1, Bh1, N);      // H1s

    // ---- Layer 2 ----
    gather128<<<wblk, 256, 0, stream>>>(
        Bh1, cntI, cntO, packed, nullptr, 0, 0, 0, Bh0, N); // agg2
    gemm_mfma<128, 128, false><<<gblk, 256, 0, stream>>>(
        Bh0, WT2, nullptr, cntI, b2, 1, cntO, Bh1, N);      // H2s

    // ---- Layer 3 ----
    gemm_mfma<128, 64, false><<<gblk, 256, 0, stream>>>(
        Bh1, WT3, nullptr, nullptr, nullptr, 0, nullptr, Bh0, N);  // M3
    gather64<<<wblk, 256, 0, stream>>>(
        Bh0, cntI, packed, b3, (float*)d_out, N);
}

// Round 10
// 321.013 us; speedup vs baseline: 1.2314x; 1.0689x over previous
//
#include <hip/hip_runtime.h>
#include <math.h>

// ---------------------------------------------------------------------------
// GCN 3x GraphConv (DGL norm='both'), N=50000, E=800000, 256->128->128->64.
// R10: branch-free padded gathers. R9's gather128 was latency-bound: mean
// in-deg 16 => the deep-unroll path (len>28) never ran; remainder loop had
// ~1 load in flight. Now packed lists are PADDED with index N (a zero row
// appended to each msg buffer, memset per launch); gathers do
// iters=ceil(len/32) with 8 fully-independent half8 row loads per 16-lane
// group (16B/lane). Padding reads hit one L2-hot zero line (~free).
// Build fused: bin_edges (src+dst one pass), lists_counts (lists + out-deg).
//   L1: M1 = f16(X*ns)@W1 ; H1s = relu(sum M1[src] *nd + b1)*ns
//   L2: agg2 = sum H1s[src] ; H2s = relu((agg2@W2)*nd + b2)*ns
//   L3: M3 = H2s@W3 ; out = sum M3[src]*nd + b3
// ---------------------------------------------------------------------------

typedef _Float16 half8 __attribute__((ext_vector_type(8)));
typedef float floatx4 __attribute__((ext_vector_type(4)));

#define TILE 4096   // edges per bin tile
#define BCAP 8192   // per-coarse-bucket capacity (avg 4096)
#define PKW  64     // packed list width per node = 128B line
#define EPT  16     // edges per thread in bin pass

// ---- fused pass 1: bin (src,dst) by dst>>8 AND src by src>>8 ----
__global__ __launch_bounds__(256) void bin_edges(
    const int* __restrict__ src, const int* __restrict__ dst, int E, int NB,
    int* __restrict__ gcurD, int* __restrict__ gcurS,
    ushort2* __restrict__ binD, unsigned short* __restrict__ binS)
{
    __shared__ int lcntD[256], loffD[256], curD[256], lbaseD[256];
    __shared__ int lcntS[256], loffS[256], curS[256], lbaseS[256];
    __shared__ int wtot[4];
    __shared__ ushort2 stageD[TILE];
    __shared__ unsigned short stageS[TILE];

    const int tid = threadIdx.x, lane = tid & 63, wave = tid >> 6;
    const int tile0 = blockIdx.x * TILE;
    const int tn = min(TILE, E - tile0);

    lcntD[tid] = 0;
    lcntS[tid] = 0;
    __syncthreads();

    unsigned short es[EPT], ed[EPT];
    unsigned char ebD[EPT], ebS[EPT];
    int nl = 0;
    for (int i = tid; i < tn; i += 256) {
        int s = src[tile0 + i], d = dst[tile0 + i];
        es[nl] = (unsigned short)s; ed[nl] = (unsigned short)d;
        ebD[nl] = (unsigned char)(d >> 8);
        ebS[nl] = (unsigned char)(s >> 8);
        nl++;
        atomicAdd(&lcntD[d >> 8], 1);
        atomicAdd(&lcntS[s >> 8], 1);
    }
    __syncthreads();

    // scan D
    {
        int v = lcntD[tid], x = v;
#pragma unroll
        for (int o = 1; o < 64; o <<= 1) {
            int t = __shfl_up(x, o, 64);
            if (lane >= o) x += t;
        }
        if (lane == 63) wtot[wave] = x;
        __syncthreads();
        if (tid == 0) {
            int a = 0;
#pragma unroll
            for (int w = 0; w < 4; w++) { int t = wtot[w]; wtot[w] = a; a += t; }
        }
        __syncthreads();
        int excl = x - v + wtot[wave];
        loffD[tid] = excl;
        curD[tid]  = excl;
    }
    __syncthreads();
    // scan S
    {
        int v = lcntS[tid], x = v;
#pragma unroll
        for (int o = 1; o < 64; o <<= 1) {
            int t = __shfl_up(x, o, 64);
            if (lane >= o) x += t;
        }
        if (lane == 63) wtot[wave] = x;
        __syncthreads();
        if (tid == 0) {
            int a = 0;
#pragma unroll
            for (int w = 0; w < 4; w++) { int t = wtot[w]; wtot[w] = a; a += t; }
        }
        __syncthreads();
        int excl = x - v + wtot[wave];
        loffS[tid] = excl;
        curS[tid]  = excl;
    }
    __syncthreads();

    for (int j = 0; j < nl; j++) {
        int pD = atomicAdd(&curD[ebD[j]], 1);
        ushort2 u; u.x = es[j]; u.y = ed[j];
        stageD[pD] = u;
        int pS = atomicAdd(&curS[ebS[j]], 1);
        stageS[pS] = es[j];
    }
    if (tid < NB) {
        if (lcntD[tid] > 0) lbaseD[tid] = atomicAdd(&gcurD[tid], lcntD[tid]);
        if (lcntS[tid] > 0) lbaseS[tid] = atomicAdd(&gcurS[tid], lcntS[tid]);
    }
    __syncthreads();

    for (int i = tid; i < tn; i += 256) {
        // write-out D
        {
            int lo = 0, hi = NB - 1;
            while (lo < hi) {
                int mid = (lo + hi + 1) >> 1;
                if (loffD[mid] <= i) lo = mid; else hi = mid - 1;
            }
            int gi = lbaseD[lo] + (i - loffD[lo]);
            if (gi < BCAP)
                binD[(size_t)lo * BCAP + gi] = stageD[i];
        }
        // write-out S
        {
            int lo = 0, hi = NB - 1;
            while (lo < hi) {
                int mid = (lo + hi + 1) >> 1;
                if (loffS[mid] <= i) lo = mid; else hi = mid - 1;
            }
            int gi = lbaseS[lo] + (i - loffS[lo]);
            if (gi < BCAP)
                binS[(size_t)lo * BCAP + gi] = stageS[i];
        }
    }
}

// ---- fused pass 2: packed in-lists (PAD-filled) + cntI + cntO ----
__global__ __launch_bounds__(256) void lists_counts(
    const ushort2* __restrict__ binD, const int* __restrict__ gcurD,
    const unsigned short* __restrict__ binS, const int* __restrict__ gcurS,
    unsigned short* __restrict__ packed, int* __restrict__ cntI,
    int* __restrict__ cntO, int N, unsigned short padv)
{
    __shared__ unsigned short stage[256 * PKW];   // 32 KB
    __shared__ int lcnt[256];
    __shared__ int h[256];
    const int tid = threadIdx.x;
    const int b = blockIdx.x;
    const int node0 = b << 8;

    lcnt[tid] = 0;
    h[tid] = 0;
    for (int i = tid; i < 256 * PKW; i += 256)
        stage[i] = padv;                          // pad slots -> zero row
    __syncthreads();

    const int nD = min(gcurD[b], BCAP);
    const ushort2* ebD = binD + (size_t)b * BCAP;
    for (int i = tid; i < nD; i += 256) {
        ushort2 e = ebD[i];
        int ld = (int)e.y - node0;
        int p = atomicAdd(&lcnt[ld], 1);
        if (p < PKW) stage[ld * PKW + p] = e.x;
    }
    const int nS = min(gcurS[b], BCAP);
    const unsigned short* ebS = binS + (size_t)b * BCAP;
    for (int i = tid; i < nS; i += 256)
        atomicAdd(&h[(int)ebS[i] - node0], 1);
    __syncthreads();

    int node = node0 + tid;
    if (node < N) {
        cntI[node] = min(lcnt[tid], PKW);
        cntO[node] = h[tid];
    }
    const int wave = tid >> 6, lane = tid & 63;
    for (int ld = wave; ld < 256; ld += 4) {
        int nd = node0 + ld;
        if (nd < N)
            packed[(size_t)nd * PKW + lane] = stage[ld * PKW + lane];
    }
}

// Fused f16 transpose of W1,W2,W3: WT[n*K+k] = (f16) W[k*NC+n]
__global__ __launch_bounds__(256) void wprep(
    const float* __restrict__ W1, const float* __restrict__ W2,
    const float* __restrict__ W3, _Float16* __restrict__ WT1,
    _Float16* __restrict__ WT2, _Float16* __restrict__ WT3)
{
    int i = blockIdx.x * 256 + threadIdx.x;
    if (i < 256 * 128) {
        int k = i / 128, n = i - k * 128;
        WT1[(size_t)n * 256 + k] = (_Float16)W1[i];
    } else if (i < 256 * 128 + 128 * 128) {
        int r = i - 256 * 128;
        int k = r / 128, n = r - k * 128;
        WT2[(size_t)n * 128 + k] = (_Float16)W2[r];
    } else if (i < 256 * 128 + 128 * 128 + 128 * 64) {
        int r = i - 256 * 128 - 128 * 128;
        int k = r / 64, n = r - k * 64;
        WT3[(size_t)n * 128 + k] = (_Float16)W3[r];
    }
}

// ---------------------------------------------------------------------------
// LDS-staged MFMA GEMM (verified R9): C[M,NC] f16 = A[M,K] @ W (WT[NC,K]).
// Block = 4 waves x 128 rows; wave = 2 m-tiles. B staged per 128-K chunk.
// ---------------------------------------------------------------------------
template<int K, int NC, bool A_FP32>
__global__ __launch_bounds__(256) void gemm_mfma(
    const void* __restrict__ A_, const _Float16* __restrict__ WT,
    const int* __restrict__ cnt_rs,
    const int* __restrict__ cnt_nd, const float* __restrict__ bias,
    int do_relu, const int* __restrict__ cnt_ns,
    _Float16* __restrict__ C, int M)
{
    constexpr int NT  = NC / 16;
    constexpr int KC  = 128;
    constexpr int LDW = KC + 8;
    __shared__ _Float16 Bs[NC * LDW];

    const int tid  = threadIdx.x;
    const int wave = tid >> 6;
    const int lane = tid & 63;
    const int quad = lane >> 4;
    const int l16  = lane & 15;

    const int row_base = blockIdx.x * 128 + wave * 32;
    const int ar0 = min(row_base + l16, M - 1);
    const int ar1 = min(row_base + 16 + l16, M - 1);

    floatx4 acc[2][NT];
#pragma unroll
    for (int m = 0; m < 2; m++)
#pragma unroll
        for (int t = 0; t < NT; t++)
            acc[m][t] = (floatx4){0.f, 0.f, 0.f, 0.f};

    float rs0 = 1.0f, rs1 = 1.0f;
    if (A_FP32 && cnt_rs) {
        rs0 = rsqrtf(fmaxf((float)cnt_rs[ar0], 1.0f));
        rs1 = rsqrtf(fmaxf((float)cnt_rs[ar1], 1.0f));
    }

    const float*    Af = (const float*)A_;
    const _Float16* Ah = (const _Float16*)A_;

    for (int kc = 0; kc < K; kc += KC) {
#pragma unroll
        for (int s = tid; s < NC * (KC / 8); s += 256) {
            int row  = s >> 4;
            int col8 = s & 15;
            half8 v = *(const half8*)&WT[(size_t)row * K + kc + col8 * 8];
            *(half8*)&Bs[row * LDW + col8 * 8] = v;
        }
        __syncthreads();
#pragma unroll
        for (int k0 = 0; k0 < KC; k0 += 32) {
            half8 a0, a1;
            if (A_FP32) {
                const float* p0 = &Af[(size_t)ar0 * K + kc + k0 + quad * 8];
                const float* p1 = &Af[(size_t)ar1 * K + kc + k0 + quad * 8];
                float4 f0 = *(const float4*)p0;
                float4 f1 = *(const float4*)(p0 + 4);
                float4 g0 = *(const float4*)p1;
                float4 g1 = *(const float4*)(p1 + 4);
                a0[0] = (_Float16)(f0.x * rs0); a0[1] = (_Float16)(f0.y * rs0);
                a0[2] = (_Float16)(f0.z * rs0); a0[3] = (_Float16)(f0.w * rs0);
                a0[4] = (_Float16)(f1.x * rs0); a0[5] = (_Float16)(f1.y * rs0);
                a0[6] = (_Float16)(f1.z * rs0); a0[7] = (_Float16)(f1.w * rs0);
                a1[0] = (_Float16)(g0.x * rs1); a1[1] = (_Float16)(g0.y * rs1);
                a1[2] = (_Float16)(g0.z * rs1); a1[3] = (_Float16)(g0.w * rs1);
                a1[4] = (_Float16)(g1.x * rs1); a1[5] = (_Float16)(g1.y * rs1);
                a1[6] = (_Float16)(g1.z * rs1); a1[7] = (_Float16)(g1.w * rs1);
            } else {
                a0 = *(const half8*)&Ah[(size_t)ar0 * K + kc + k0 + quad * 8];
                a1 = *(const half8*)&Ah[(size_t)ar1 * K + kc + k0 + quad * 8];
            }
#pragma unroll
            for (int t = 0; t < NT; t++) {
                half8 b = *(const half8*)&Bs[(t * 16 + l16) * LDW + k0 + quad * 8];
                acc[0][t] = __builtin_amdgcn_mfma_f32_16x16x32_f16(a0, b, acc[0][t], 0, 0, 0);
                acc[1][t] = __builtin_amdgcn_mfma_f32_16x16x32_f16(a1, b, acc[1][t], 0, 0, 0);
            }
        }
        __syncthreads();
    }

#pragma unroll
    for (int m = 0; m < 2; m++) {
#pragma unroll
        for (int t = 0; t < NT; t++) {
            int col = t * 16 + l16;
            float bv = bias ? bias[col] : 0.f;
#pragma unroll
            for (int r = 0; r < 4; r++) {
                int row_o = row_base + m * 16 + quad * 4 + r;
                if (row_o < M) {
                    float v = acc[m][t][r];
                    if (cnt_nd) v *= rsqrtf(fmaxf((float)cnt_nd[row_o], 1.0f));
                    v += bv;
                    if (do_relu) v = fmaxf(v, 0.f);
                    if (cnt_ns) v *= rsqrtf(fmaxf((float)cnt_ns[row_o], 1.0f));
                    C[(size_t)row_o * NC + col] = (_Float16)v;
                }
            }
        }
    }
}

// ---------------------------------------------------------------------------
// F=128 gather: wave/node, 4 groups x 16 lanes x half8 (16B). Lists padded
// with idx N (zero row) -> branch-free 8-deep independent loads per group.
// ---------------------------------------------------------------------------
__global__ __launch_bounds__(256) void gather128(
    const _Float16* __restrict__ msg, const int* __restrict__ cntI,
    const int* __restrict__ cntO, const unsigned short* __restrict__ packed,
    const float* __restrict__ bias, int do_relu, int use_nd, int use_ns,
    _Float16* __restrict__ out, int N)
{
    int node = (blockIdx.x * 256 + threadIdx.x) >> 6;
    if (node >= N) return;
    int lane = threadIdx.x & 63;
    int grp = lane >> 4, l16 = lane & 15;

    int len = cntI[node];
    const unsigned short* bl = packed + (size_t)node * PKW;
    const half8* mp = (const half8*)msg;   // 16 half8 per row

    float a[8];
#pragma unroll
    for (int h = 0; h < 8; h++) a[h] = 0.f;

    int iters = (len + 31) >> 5;
    if (iters < 1) iters = 1;
    for (int it = 0; it < iters; it++) {
        int j = it * 32 + grp;
        int s0 = bl[j],      s1 = bl[j + 4],  s2 = bl[j + 8],  s3 = bl[j + 12];
        int s4 = bl[j + 16], s5 = bl[j + 20], s6 = bl[j + 24], s7 = bl[j + 28];
        half8 v0 = mp[(size_t)s0 * 16 + l16];
        half8 v1 = mp[(size_t)s1 * 16 + l16];
        half8 v2 = mp[(size_t)s2 * 16 + l16];
        half8 v3 = mp[(size_t)s3 * 16 + l16];
        half8 v4 = mp[(size_t)s4 * 16 + l16];
        half8 v5 = mp[(size_t)s5 * 16 + l16];
        half8 v6 = mp[(size_t)s6 * 16 + l16];
        half8 v7 = mp[(size_t)s7 * 16 + l16];
#pragma unroll
        for (int h = 0; h < 8; h++)
            a[h] += (((float)v0[h] + (float)v1[h]) + ((float)v2[h] + (float)v3[h]))
                  + (((float)v4[h] + (float)v5[h]) + ((float)v6[h] + (float)v7[h]));
    }
#pragma unroll
    for (int h = 0; h < 8; h++) {
        a[h] += __shfl_xor(a[h], 16);
        a[h] += __shfl_xor(a[h], 32);
    }

    if (grp == 0) {
        float sc = use_nd ? rsqrtf(fmaxf((float)len, 1.0f)) : 1.0f;
        float pp = use_ns ? rsqrtf(fmaxf((float)cntO[node], 1.0f)) : 1.0f;
        half8 rv;
#pragma unroll
        for (int h = 0; h < 8; h++) {
            float bv = bias ? bias[l16 * 8 + h] : 0.f;
            float r = a[h] * sc + bv;
            if (do_relu) r = fmaxf(r, 0.f);
            rv[h] = (_Float16)(r * pp);
        }
        ((half8*)out)[(size_t)node * 16 + l16] = rv;
    }
}

// F=64 gather: 8 groups x 8 lanes x half8; 4 indep loads/group; fp32 out.
__global__ __launch_bounds__(256) void gather64(
    const _Float16* __restrict__ msg, const int* __restrict__ cntI,
    const unsigned short* __restrict__ packed, const float* __restrict__ bias,
    float* __restrict__ out, int N)
{
    int node = (blockIdx.x * 256 + threadIdx.x) >> 6;
    if (node >= N) return;
    int lane = threadIdx.x & 63;
    int grp = lane >> 3, l8 = lane & 7;

    int len = cntI[node];
    const unsigned short* bl = packed + (size_t)node * PKW;
    const half8* mp = (const half8*)msg;   // 8 half8 per row

    float a[8];
#pragma unroll
    for (int h = 0; h < 8; h++) a[h] = 0.f;

    int iters = (len + 31) >> 5;
    if (iters < 1) iters = 1;
    for (int it = 0; it < iters; it++) {
        int j = it * 32 + grp;
        int s0 = bl[j], s1 = bl[j + 8], s2 = bl[j + 16], s3 = bl[j + 24];
        half8 v0 = mp[(size_t)s0 * 8 + l8];
        half8 v1 = mp[(size_t)s1 * 8 + l8];
        half8 v2 = mp[(size_t)s2 * 8 + l8];
        half8 v3 = mp[(size_t)s3 * 8 + l8];
#pragma unroll
        for (int h = 0; h < 8; h++)
            a[h] += ((float)v0[h] + (float)v1[h]) + ((float)v2[h] + (float)v3[h]);
    }
#pragma unroll
    for (int h = 0; h < 8; h++) {
        a[h] += __shfl_xor(a[h], 8);
        a[h] += __shfl_xor(a[h], 16);
        a[h] += __shfl_xor(a[h], 32);
    }

    if (grp == 0) {
        float sc = rsqrtf(fmaxf((float)len, 1.0f));
        float4 r0, r1;
        r0.x = a[0] * sc + bias[l8 * 8 + 0];
        r0.y = a[1] * sc + bias[l8 * 8 + 1];
        r0.z = a[2] * sc + bias[l8 * 8 + 2];
        r0.w = a[3] * sc + bias[l8 * 8 + 3];
        r1.x = a[4] * sc + bias[l8 * 8 + 4];
        r1.y = a[5] * sc + bias[l8 * 8 + 5];
        r1.z = a[6] * sc + bias[l8 * 8 + 6];
        r1.w = a[7] * sc + bias[l8 * 8 + 7];
        float4* op = (float4*)&out[(size_t)node * 64 + l8 * 8];
        op[0] = r0;
        op[1] = r1;
    }
}

extern "C" void kernel_launch(void* const* d_in, const int* in_sizes, int n_in,
                              void* d_out, int out_size, void* d_ws, size_t ws_size,
                              hipStream_t stream)
{
    const float* X  = (const float*)d_in[0];
    const float* W1 = (const float*)d_in[1];
    const float* b1 = (const float*)d_in[2];
    const float* W2 = (const float*)d_in[3];
    const float* b2 = (const float*)d_in[4];
    const float* W3 = (const float*)d_in[5];
    const float* b3 = (const float*)d_in[6];
    const int*   src = (const int*)d_in[7];
    const int*   dst = (const int*)d_in[8];

    const int N = in_sizes[0] / 256;   // 50000
    const int E = in_sizes[7];         // 800000
    const int NB = (N + 255) >> 8;     // 196 coarse buckets

    char* base = (char*)d_ws;
    size_t cur = 0;
    auto alloc = [&](size_t bytes) -> void* {
        void* p = base + cur;
        cur += (bytes + 255) & ~(size_t)255;
        return p;
    };
    int* gcur2 = (int*)alloc((size_t)2 * 256 * 4);
    int* gcurD = gcur2;
    int* gcurS = gcur2 + 256;
    ushort2*        binD   = (ushort2*)alloc((size_t)NB * BCAP * 4);
    unsigned short* binS   = (unsigned short*)alloc((size_t)NB * BCAP * 2);
    unsigned short* packed = (unsigned short*)alloc((size_t)N * PKW * 2);
    int* cntO = (int*)alloc((size_t)N * 4);
    int* cntI = (int*)alloc((size_t)N * 4);
    _Float16* Bh0 = (_Float16*)alloc(((size_t)N + 1) * 128 * 2);  // +zero row
    _Float16* Bh1 = (_Float16*)alloc(((size_t)N + 1) * 128 * 2);
    _Float16* WT1 = (_Float16*)alloc((size_t)256 * 128 * 2);
    _Float16* WT2 = (_Float16*)alloc((size_t)128 * 128 * 2);
    _Float16* WT3 = (_Float16*)alloc((size_t)128 * 64 * 2);

    const int tblk = (E + TILE - 1) / TILE;
    const int gblk = (N + 127) / 128;
    const int wblk = (N + 3) / 4;

    hipMemsetAsync(gcur2, 0, 2 * 256 * sizeof(int), stream);
    // zero rows (row index N) for the 128-wide views of Bh0/Bh1
    hipMemsetAsync(Bh0 + (size_t)N * 128, 0, 256, stream);
    hipMemsetAsync(Bh1 + (size_t)N * 128, 0, 256, stream);

    wprep<<<(256*128 + 128*128 + 128*64 + 255) / 256, 256, 0, stream>>>(
        W1, W2, W3, WT1, WT2, WT3);
    bin_edges<<<tblk, 256, 0, stream>>>(src, dst, E, NB, gcurD, gcurS, binD, binS);
    lists_counts<<<NB, 256, 0, stream>>>(binD, gcurD, binS, gcurS,
                                         packed, cntI, cntO, N,
                                         (unsigned short)N);

    // ---- Layer 1 ----
    gemm_mfma<256, 128, true><<<gblk, 256, 0, stream>>>(
        X, WT1, cntO, nullptr, nullptr, 0, nullptr, Bh0, N);
    gather128<<<wblk, 256, 0, stream>>>(
        Bh0, cntI, cntO, packed, b1, 1, 1, 1, Bh1, N);      // H1s

    // ---- Layer 2 ----
    gather128<<<wblk, 256, 0, stream>>>(
        Bh1, cntI, cntO, packed, nullptr, 0, 0, 0, Bh0, N); // agg2
    gemm_mfma<128, 128, false><<<gblk, 256, 0, stream>>>(
        Bh0, WT2, nullptr, cntI, b2, 1, cntO, Bh1, N);      // H2s

    // ---- Layer 3 ----
    gemm_mfma<128, 64, false><<<gblk, 256, 0, stream>>>(
        Bh1, WT3, nullptr, nullptr, nullptr, 0, nullptr, Bh0, N);  // M3
    // zero row for the 64-wide view of Bh0 (after M3 is written)
    hipMemsetAsync(Bh0 + (size_t)N * 64, 0, 128, stream);
    gather64<<<wblk, 256, 0, stream>>>(
        Bh0, cntI, packed, b3, (float*)d_out, N);
}

// Round 11
// 303.663 us; speedup vs baseline: 1.3018x; 1.0571x over previous
//
#include <hip/hip_runtime.h>
#include <math.h>

// ---------------------------------------------------------------------------
// GCN 3x GraphConv (DGL norm='both'), N=50000, E=800000, 256->128->128->64.
// R11: R10 + (a) bin_edges TILE 4096->1024: R10 showed 196 blocks < 256 CUs
// (Occupancy 7%) — build was chip-idle-bound; now 782 blocks, 4x shorter
// serial loops, ~14KB LDS. (b) zero memset dispatches: wprep zeroes gcur +
// 128-wide pad rows; gemm3 runs M=N+1 so its zero A-row emits the 64-wide
// pad row for free. 9 dispatches total.
//   L1: M1 = f16(X*ns)@W1 ; H1s = relu(sum M1[src] *nd + b1)*ns
//   L2: agg2 = sum H1s[src] ; H2s = relu((agg2@W2)*nd + b2)*ns
//   L3: M3 = H2s@W3 ; out = sum M3[src]*nd + b3
// ---------------------------------------------------------------------------

typedef _Float16 half8 __attribute__((ext_vector_type(8)));
typedef float floatx4 __attribute__((ext_vector_type(4)));

#define TILE 1024   // edges per bin tile (782 blocks -> >2 per CU)
#define BCAP 8192   // per-coarse-bucket capacity (avg 4096)
#define PKW  64     // packed list width per node = 128B line
#define EPT  4      // edges per thread in bin pass (TILE/256)

// ---- fused pass 1: bin (src,dst) by dst>>8 AND src by src>>8 ----
__global__ __launch_bounds__(256) void bin_edges(
    const int* __restrict__ src, const int* __restrict__ dst, int E, int NB,
    int* __restrict__ gcurD, int* __restrict__ gcurS,
    ushort2* __restrict__ binD, unsigned short* __restrict__ binS)
{
    __shared__ int lcntD[256], loffD[256], curD[256], lbaseD[256];
    __shared__ int lcntS[256], loffS[256], curS[256], lbaseS[256];
    __shared__ int wtot[4];
    __shared__ ushort2 stageD[TILE];
    __shared__ unsigned short stageS[TILE];

    const int tid = threadIdx.x, lane = tid & 63, wave = tid >> 6;
    const int tile0 = blockIdx.x * TILE;
    const int tn = min(TILE, E - tile0);

    lcntD[tid] = 0;
    lcntS[tid] = 0;
    __syncthreads();

    unsigned short es[EPT], ed[EPT];
    unsigned char ebD[EPT], ebS[EPT];
    int nl = 0;
    for (int i = tid; i < tn; i += 256) {
        int s = src[tile0 + i], d = dst[tile0 + i];
        es[nl] = (unsigned short)s; ed[nl] = (unsigned short)d;
        ebD[nl] = (unsigned char)(d >> 8);
        ebS[nl] = (unsigned char)(s >> 8);
        nl++;
        atomicAdd(&lcntD[d >> 8], 1);
        atomicAdd(&lcntS[s >> 8], 1);
    }
    __syncthreads();

    // scan D
    {
        int v = lcntD[tid], x = v;
#pragma unroll
        for (int o = 1; o < 64; o <<= 1) {
            int t = __shfl_up(x, o, 64);
            if (lane >= o) x += t;
        }
        if (lane == 63) wtot[wave] = x;
        __syncthreads();
        if (tid == 0) {
            int a = 0;
#pragma unroll
            for (int w = 0; w < 4; w++) { int t = wtot[w]; wtot[w] = a; a += t; }
        }
        __syncthreads();
        int excl = x - v + wtot[wave];
        loffD[tid] = excl;
        curD[tid]  = excl;
    }
    __syncthreads();
    // scan S
    {
        int v = lcntS[tid], x = v;
#pragma unroll
        for (int o = 1; o < 64; o <<= 1) {
            int t = __shfl_up(x, o, 64);
            if (lane >= o) x += t;
        }
        if (lane == 63) wtot[wave] = x;
        __syncthreads();
        if (tid == 0) {
            int a = 0;
#pragma unroll
            for (int w = 0; w < 4; w++) { int t = wtot[w]; wtot[w] = a; a += t; }
        }
        __syncthreads();
        int excl = x - v + wtot[wave];
        loffS[tid] = excl;
        curS[tid]  = excl;
    }
    __syncthreads();

    for (int j = 0; j < nl; j++) {
        int pD = atomicAdd(&curD[ebD[j]], 1);
        ushort2 u; u.x = es[j]; u.y = ed[j];
        stageD[pD] = u;
        int pS = atomicAdd(&curS[ebS[j]], 1);
        stageS[pS] = es[j];
    }
    if (tid < NB) {
        if (lcntD[tid] > 0) lbaseD[tid] = atomicAdd(&gcurD[tid], lcntD[tid]);
        if (lcntS[tid] > 0) lbaseS[tid] = atomicAdd(&gcurS[tid], lcntS[tid]);
    }
    __syncthreads();

    for (int i = tid; i < tn; i += 256) {
        {
            int lo = 0, hi = NB - 1;
            while (lo < hi) {
                int mid = (lo + hi + 1) >> 1;
                if (loffD[mid] <= i) lo = mid; else hi = mid - 1;
            }
            int gi = lbaseD[lo] + (i - loffD[lo]);
            if (gi < BCAP)
                binD[(size_t)lo * BCAP + gi] = stageD[i];
        }
        {
            int lo = 0, hi = NB - 1;
            while (lo < hi) {
                int mid = (lo + hi + 1) >> 1;
                if (loffS[mid] <= i) lo = mid; else hi = mid - 1;
            }
            int gi = lbaseS[lo] + (i - loffS[lo]);
            if (gi < BCAP)
                binS[(size_t)lo * BCAP + gi] = stageS[i];
        }
    }
}

// ---- fused pass 2: packed in-lists (pad-filled) + cntI + cntO ----
__global__ __launch_bounds__(256) void lists_counts(
    const ushort2* __restrict__ binD, const int* __restrict__ gcurD,
    const unsigned short* __restrict__ binS, const int* __restrict__ gcurS,
    unsigned short* __restrict__ packed, int* __restrict__ cntI,
    int* __restrict__ cntO, int N, unsigned short padv)
{
    __shared__ unsigned short stage[256 * PKW];   // 32 KB
    __shared__ int lcnt[256];
    __shared__ int h[256];
    const int tid = threadIdx.x;
    const int b = blockIdx.x;
    const int node0 = b << 8;

    lcnt[tid] = 0;
    h[tid] = 0;
    for (int i = tid; i < 256 * PKW; i += 256)
        stage[i] = padv;                          // pad slots -> zero row
    __syncthreads();

    const int nD = min(gcurD[b], BCAP);
    const ushort2* ebD = binD + (size_t)b * BCAP;
    for (int i = tid; i < nD; i += 256) {
        ushort2 e = ebD[i];
        int ld = (int)e.y - node0;
        int p = atomicAdd(&lcnt[ld], 1);
        if (p < PKW) stage[ld * PKW + p] = e.x;
    }
    const int nS = min(gcurS[b], BCAP);
    const unsigned short* ebS = binS + (size_t)b * BCAP;
    for (int i = tid; i < nS; i += 256)
        atomicAdd(&h[(int)ebS[i] - node0], 1);
    __syncthreads();

    int node = node0 + tid;
    if (node < N) {
        cntI[node] = min(lcnt[tid], PKW);
        cntO[node] = h[tid];
    }
    const int wave = tid >> 6, lane = tid & 63;
    for (int ld = wave; ld < 256; ld += 4) {
        int nd = node0 + ld;
        if (nd < N)
            packed[(size_t)nd * PKW + lane] = stage[ld * PKW + lane];
    }
}

// Fused weight transpose + workspace zeroing (replaces all memsets):
// gcur (512 ints), Bh0/Bh1 128-wide pad rows (128 halfs each).
__global__ __launch_bounds__(256) void wprep(
    const float* __restrict__ W1, const float* __restrict__ W2,
    const float* __restrict__ W3, _Float16* __restrict__ WT1,
    _Float16* __restrict__ WT2, _Float16* __restrict__ WT3,
    int* __restrict__ gcur, _Float16* __restrict__ z0,
    _Float16* __restrict__ z1)
{
    int i = blockIdx.x * 256 + threadIdx.x;
    if (i < 512) gcur[i] = 0;
    else if (i < 640) z0[i - 512] = (_Float16)0.f;
    else if (i < 768) z1[i - 640] = (_Float16)0.f;
    if (i < 256 * 128) {
        int k = i / 128, n = i - k * 128;
        WT1[(size_t)n * 256 + k] = (_Float16)W1[i];
    } else if (i < 256 * 128 + 128 * 128) {
        int r = i - 256 * 128;
        int k = r / 128, n = r - k * 128;
        WT2[(size_t)n * 128 + k] = (_Float16)W2[r];
    } else if (i < 256 * 128 + 128 * 128 + 128 * 64) {
        int r = i - 256 * 128 - 128 * 128;
        int k = r / 64, n = r - k * 64;
        WT3[(size_t)n * 128 + k] = (_Float16)W3[r];
    }
}

// ---------------------------------------------------------------------------
// LDS-staged MFMA GEMM (verified R9/R10): C[M,NC] f16 = A[M,K] @ WT[NC,K].
// Block = 4 waves x 128 rows; wave = 2 m-tiles. B staged per 128-K chunk.
// ---------------------------------------------------------------------------
template<int K, int NC, bool A_FP32>
__global__ __launch_bounds__(256) void gemm_mfma(
    const void* __restrict__ A_, const _Float16* __restrict__ WT,
    const int* __restrict__ cnt_rs,
    const int* __restrict__ cnt_nd, const float* __restrict__ bias,
    int do_relu, const int* __restrict__ cnt_ns,
    _Float16* __restrict__ C, int M)
{
    constexpr int NT  = NC / 16;
    constexpr int KC  = 128;
    constexpr int LDW = KC + 8;
    __shared__ _Float16 Bs[NC * LDW];

    const int tid  = threadIdx.x;
    const int wave = tid >> 6;
    const int lane = tid & 63;
    const int quad = lane >> 4;
    const int l16  = lane & 15;

    const int row_base = blockIdx.x * 128 + wave * 32;
    const int ar0 = min(row_base + l16, M - 1);
    const int ar1 = min(row_base + 16 + l16, M - 1);

    floatx4 acc[2][NT];
#pragma unroll
    for (int m = 0; m < 2; m++)
#pragma unroll
        for (int t = 0; t < NT; t++)
            acc[m][t] = (floatx4){0.f, 0.f, 0.f, 0.f};

    float rs0 = 1.0f, rs1 = 1.0f;
    if (A_FP32 && cnt_rs) {
        rs0 = rsqrtf(fmaxf((float)cnt_rs[ar0], 1.0f));
        rs1 = rsqrtf(fmaxf((float)cnt_rs[ar1], 1.0f));
    }

    const float*    Af = (const float*)A_;
    const _Float16* Ah = (const _Float16*)A_;

    for (int kc = 0; kc < K; kc += KC) {
#pragma unroll
        for (int s = tid; s < NC * (KC / 8); s += 256) {
            int row  = s >> 4;
            int col8 = s & 15;
            half8 v = *(const half8*)&WT[(size_t)row * K + kc + col8 * 8];
            *(half8*)&Bs[row * LDW + col8 * 8] = v;
        }
        __syncthreads();
#pragma unroll
        for (int k0 = 0; k0 < KC; k0 += 32) {
            half8 a0, a1;
            if (A_FP32) {
                const float* p0 = &Af[(size_t)ar0 * K + kc + k0 + quad * 8];
                const float* p1 = &Af[(size_t)ar1 * K + kc + k0 + quad * 8];
                float4 f0 = *(const float4*)p0;
                float4 f1 = *(const float4*)(p0 + 4);
                float4 g0 = *(const float4*)p1;
                float4 g1 = *(const float4*)(p1 + 4);
                a0[0] = (_Float16)(f0.x * rs0); a0[1] = (_Float16)(f0.y * rs0);
                a0[2] = (_Float16)(f0.z * rs0); a0[3] = (_Float16)(f0.w * rs0);
                a0[4] = (_Float16)(f1.x * rs0); a0[5] = (_Float16)(f1.y * rs0);
                a0[6] = (_Float16)(f1.z * rs0); a0[7] = (_Float16)(f1.w * rs0);
                a1[0] = (_Float16)(g0.x * rs1); a1[1] = (_Float16)(g0.y * rs1);
                a1[2] = (_Float16)(g0.z * rs1); a1[3] = (_Float16)(g0.w * rs1);
                a1[4] = (_Float16)(g1.x * rs1); a1[5] = (_Float16)(g1.y * rs1);
                a1[6] = (_Float16)(g1.z * rs1); a1[7] = (_Float16)(g1.w * rs1);
            } else {
                a0 = *(const half8*)&Ah[(size_t)ar0 * K + kc + k0 + quad * 8];
                a1 = *(const half8*)&Ah[(size_t)ar1 * K + kc + k0 + quad * 8];
            }
#pragma unroll
            for (int t = 0; t < NT; t++) {
                half8 b = *(const half8*)&Bs[(t * 16 + l16) * LDW + k0 + quad * 8];
                acc[0][t] = __builtin_amdgcn_mfma_f32_16x16x32_f16(a0, b, acc[0][t], 0, 0, 0);
                acc[1][t] = __builtin_amdgcn_mfma_f32_16x16x32_f16(a1, b, acc[1][t], 0, 0, 0);
            }
        }
        __syncthreads();
    }

#pragma unroll
    for (int m = 0; m < 2; m++) {
#pragma unroll
        for (int t = 0; t < NT; t++) {
            int col = t * 16 + l16;
            float bv = bias ? bias[col] : 0.f;
#pragma unroll
            for (int r = 0; r < 4; r++) {
                int row_o = row_base + m * 16 + quad * 4 + r;
                if (row_o < M) {
                    float v = acc[m][t][r];
                    if (cnt_nd) v *= rsqrtf(fmaxf((float)cnt_nd[row_o], 1.0f));
                    v += bv;
                    if (do_relu) v = fmaxf(v, 0.f);
                    if (cnt_ns) v *= rsqrtf(fmaxf((float)cnt_ns[row_o], 1.0f));
                    C[(size_t)row_o * NC + col] = (_Float16)v;
                }
            }
        }
    }
}

// ---------------------------------------------------------------------------
// F=128 gather: wave/node, 4 groups x 16 lanes x half8 (16B). Lists padded
// with idx N (zero row) -> branch-free 8-deep independent loads per group.
// ---------------------------------------------------------------------------
__global__ __launch_bounds__(256) void gather128(
    const _Float16* __restrict__ msg, const int* __restrict__ cntI,
    const int* __restrict__ cntO, const unsigned short* __restrict__ packed,
    const float* __restrict__ bias, int do_relu, int use_nd, int use_ns,
    _Float16* __restrict__ out, int N)
{
    int node = (blockIdx.x * 256 + threadIdx.x) >> 6;
    if (node >= N) return;
    int lane = threadIdx.x & 63;
    int grp = lane >> 4, l16 = lane & 15;

    int len = cntI[node];
    const unsigned short* bl = packed + (size_t)node * PKW;
    const half8* mp = (const half8*)msg;   // 16 half8 per row

    float a[8];
#pragma unroll
    for (int h = 0; h < 8; h++) a[h] = 0.f;

    int iters = (len + 31) >> 5;
    if (iters < 1) iters = 1;
    for (int it = 0; it < iters; it++) {
        int j = it * 32 + grp;
        int s0 = bl[j],      s1 = bl[j + 4],  s2 = bl[j + 8],  s3 = bl[j + 12];
        int s4 = bl[j + 16], s5 = bl[j + 20], s6 = bl[j + 24], s7 = bl[j + 28];
        half8 v0 = mp[(size_t)s0 * 16 + l16];
        half8 v1 = mp[(size_t)s1 * 16 + l16];
        half8 v2 = mp[(size_t)s2 * 16 + l16];
        half8 v3 = mp[(size_t)s3 * 16 + l16];
        half8 v4 = mp[(size_t)s4 * 16 + l16];
        half8 v5 = mp[(size_t)s5 * 16 + l16];
        half8 v6 = mp[(size_t)s6 * 16 + l16];
        half8 v7 = mp[(size_t)s7 * 16 + l16];
#pragma unroll
        for (int h = 0; h < 8; h++)
            a[h] += (((float)v0[h] + (float)v1[h]) + ((float)v2[h] + (float)v3[h]))
                  + (((float)v4[h] + (float)v5[h]) + ((float)v6[h] + (float)v7[h]));
    }
#pragma unroll
    for (int h = 0; h < 8; h++) {
        a[h] += __shfl_xor(a[h], 16);
        a[h] += __shfl_xor(a[h], 32);
    }

    if (grp == 0) {
        float sc = use_nd ? rsqrtf(fmaxf((float)len, 1.0f)) : 1.0f;
        float pp = use_ns ? rsqrtf(fmaxf((float)cntO[node], 1.0f)) : 1.0f;
        half8 rv;
#pragma unroll
        for (int h = 0; h < 8; h++) {
            float bv = bias ? bias[l16 * 8 + h] : 0.f;
            float r = a[h] * sc + bv;
            if (do_relu) r = fmaxf(r, 0.f);
            rv[h] = (_Float16)(r * pp);
        }
        ((half8*)out)[(size_t)node * 16 + l16] = rv;
    }
}

// F=64 gather: 8 groups x 8 lanes x half8; 4 indep loads/group; fp32 out.
__global__ __launch_bounds__(256) void gather64(
    const _Float16* __restrict__ msg, const int* __restrict__ cntI,
    const unsigned short* __restrict__ packed, const float* __restrict__ bias,
    float* __restrict__ out, int N)
{
    int node = (blockIdx.x * 256 + threadIdx.x) >> 6;
    if (node >= N) return;
    int lane = threadIdx.x & 63;
    int grp = lane >> 3, l8 = lane & 7;

    int len = cntI[node];
    const unsigned short* bl = packed + (size_t)node * PKW;
    const half8* mp = (const half8*)msg;   // 8 half8 per row

    float a[8];
#pragma unroll
    for (int h = 0; h < 8; h++) a[h] = 0.f;

    int iters = (len + 31) >> 5;
    if (iters < 1) iters = 1;
    for (int it = 0; it < iters; it++) {
        int j = it * 32 + grp;
        int s0 = bl[j], s1 = bl[j + 8], s2 = bl[j + 16], s3 = bl[j + 24];
        half8 v0 = mp[(size_t)s0 * 8 + l8];
        half8 v1 = mp[(size_t)s1 * 8 + l8];
        half8 v2 = mp[(size_t)s2 * 8 + l8];
        half8 v3 = mp[(size_t)s3 * 8 + l8];
#pragma unroll
        for (int h = 0; h < 8; h++)
            a[h] += ((float)v0[h] + (float)v1[h]) + ((float)v2[h] + (float)v3[h]);
    }
#pragma unroll
    for (int h = 0; h < 8; h++) {
        a[h] += __shfl_xor(a[h], 8);
        a[h] += __shfl_xor(a[h], 16);
        a[h] += __shfl_xor(a[h], 32);
    }

    if (grp == 0) {
        float sc = rsqrtf(fmaxf((float)len, 1.0f));
        float4 r0, r1;
        r0.x = a[0] * sc + bias[l8 * 8 + 0];
        r0.y = a[1] * sc + bias[l8 * 8 + 1];
        r0.z = a[2] * sc + bias[l8 * 8 + 2];
        r0.w = a[3] * sc + bias[l8 * 8 + 3];
        r1.x = a[4] * sc + bias[l8 * 8 + 4];
        r1.y = a[5] * sc + bias[l8 * 8 + 5];
        r1.z = a[6] * sc + bias[l8 * 8 + 6];
        r1.w = a[7] * sc + bias[l8 * 8 + 7];
        float4* op = (float4*)&out[(size_t)node * 64 + l8 * 8];
        op[0] = r0;
        op[1] = r1;
    }
}

extern "C" void kernel_launch(void* const* d_in, const int* in_sizes, int n_in,
                              void* d_out, int out_size, void* d_ws, size_t ws_size,
                              hipStream_t stream)
{
    const float* X  = (const float*)d_in[0];
    const float* W1 = (const float*)d_in[1];
    const float* b1 = (const float*)d_in[2];
    const float* W2 = (const float*)d_in[3];
    const float* b2 = (const float*)d_in[4];
    const float* W3 = (const float*)d_in[5];
    const float* b3 = (const float*)d_in[6];
    const int*   src = (const int*)d_in[7];
    const int*   dst = (const int*)d_in[8];

    const int N = in_sizes[0] / 256;   // 50000
    const int E = in_sizes[7];         // 800000
    const int NB = (N + 255) >> 8;     // 196 coarse buckets

    char* base = (char*)d_ws;
    size_t cur = 0;
    auto alloc = [&](size_t bytes) -> void* {
        void* p = base + cur;
        cur += (bytes + 255) & ~(size_t)255;
        return p;
    };
    int* gcur2 = (int*)alloc((size_t)2 * 256 * 4);
    int* gcurD = gcur2;
    int* gcurS = gcur2 + 256;
    ushort2*        binD   = (ushort2*)alloc((size_t)NB * BCAP * 4);
    unsigned short* binS   = (unsigned short*)alloc((size_t)NB * BCAP * 2);
    unsigned short* packed = (unsigned short*)alloc((size_t)N * PKW * 2);
    int* cntO = (int*)alloc((size_t)N * 4);
    int* cntI = (int*)alloc((size_t)N * 4);
    _Float16* Bh0 = (_Float16*)alloc(((size_t)N + 1) * 128 * 2);  // +pad row
    _Float16* Bh1 = (_Float16*)alloc(((size_t)N + 1) * 128 * 2);
    _Float16* WT1 = (_Float16*)alloc((size_t)256 * 128 * 2);
    _Float16* WT2 = (_Float16*)alloc((size_t)128 * 128 * 2);
    _Float16* WT3 = (_Float16*)alloc((size_t)128 * 64 * 2);

    const int tblk = (E + TILE - 1) / TILE;   // 782 tiles
    const int gblk = (N + 127) / 128;
    const int wblk = (N + 3) / 4;

    // wprep: weight transposes + zero gcur + zero 128-wide pad rows
    wprep<<<(256*128 + 128*128 + 128*64 + 255) / 256, 256, 0, stream>>>(
        W1, W2, W3, WT1, WT2, WT3,
        gcur2, Bh0 + (size_t)N * 128, Bh1 + (size_t)N * 128);
    bin_edges<<<tblk, 256, 0, stream>>>(src, dst, E, NB, gcurD, gcurS, binD, binS);
    lists_counts<<<NB, 256, 0, stream>>>(binD, gcurD, binS, gcurS,
                                         packed, cntI, cntO, N,
                                         (unsigned short)N);

    // ---- Layer 1 ----
    gemm_mfma<256, 128, true><<<gblk, 256, 0, stream>>>(
        X, WT1, cntO, nullptr, nullptr, 0, nullptr, Bh0, N);
    gather128<<<wblk, 256, 0, stream>>>(
        Bh0, cntI, cntO, packed, b1, 1, 1, 1, Bh1, N);      // H1s

    // ---- Layer 2 ----
    gather128<<<wblk, 256, 0, stream>>>(
        Bh1, cntI, cntO, packed, nullptr, 0, 0, 0, Bh0, N); // agg2
    gemm_mfma<128, 128, false><<<gblk, 256, 0, stream>>>(
        Bh0, WT2, nullptr, cntI, b2, 1, cntO, Bh1, N);      // H2s

    // ---- Layer 3 ----
    // M = N+1: row N of Bh1 is the maintained zero row -> writes the
    // 64-wide zero pad row for gather64 (no epilogue arrays -> no OOB).
    gemm_mfma<128, 64, false><<<(N + 1 + 127) / 128, 256, 0, stream>>>(
        Bh1, WT3, nullptr, nullptr, nullptr, 0, nullptr, Bh0, N + 1);  // M3
    gather64<<<wblk, 256, 0, stream>>>(
        Bh0, cntI, packed, b3, (float*)d_out, N);
}